// Round 1
// baseline (1379.736 us; speedup 1.0000x reference)
//
#include <hip/hip_runtime.h>
#include <math.h>

#define NNODES 20000
#define NEDGES 320000
#define CC 128          // channels
#define TC 384          // 3*C
#define BB 20           // basis dim
#define RCUT_F 5.0f
#define PI_F 3.14159265358979323846f

// ---------------------------------------------------------------------------
// Init: d_out[0:N*C] = q, d_out[N*C:] = mu   (float4 grid-stride copy)
// ---------------------------------------------------------------------------
__global__ __launch_bounds__(256) void init_out_kernel(
    const float4* __restrict__ q4, const float4* __restrict__ mu4,
    float4* __restrict__ out4) {
  const size_t NQ = (size_t)NNODES * CC / 4;       // 640000
  const size_t NT = NQ + (size_t)NNODES * TC / 4;  // 2560000
  size_t i = (size_t)blockIdx.x * blockDim.x + threadIdx.x;
  if (i < NQ) {
    out4[i] = q4[i];
  } else if (i < NT) {
    out4[i] = mu4[i - NQ];
  }
}

// ---------------------------------------------------------------------------
// Context net: x = silu(q@W1 + b1) @ W2 + b2      [N, 3C]
// 8 nodes per block, 128 threads. Weights stream from L2 (one read per block),
// activations broadcast from LDS via float4.
// ---------------------------------------------------------------------------
__global__ __launch_bounds__(128) void ctx_net_kernel(
    const float* __restrict__ q,
    const float* __restrict__ W1, const float* __restrict__ b1,
    const float* __restrict__ W2, const float* __restrict__ b2,
    float* __restrict__ x) {
  __shared__ __align__(16) float q_lds[8][CC];
  __shared__ __align__(16) float h_lds[8][CC];
  const int t = threadIdx.x;
  const int node0 = blockIdx.x * 8;

  #pragma unroll
  for (int n = 0; n < 8; ++n)
    q_lds[n][t] = q[(size_t)(node0 + n) * CC + t];
  __syncthreads();

  // GEMM1: h = silu(q@W1 + b1); thread t owns output column t
  float acc[8];
  {
    const float bv = b1[t];
    #pragma unroll
    for (int n = 0; n < 8; ++n) acc[n] = bv;
  }
  for (int k = 0; k < CC; k += 4) {
    float w[4];
    #pragma unroll
    for (int r = 0; r < 4; ++r) w[r] = W1[(size_t)(k + r) * CC + t];
    #pragma unroll
    for (int n = 0; n < 8; ++n) {
      const float4 qv = *reinterpret_cast<const float4*>(&q_lds[n][k]);
      acc[n] = fmaf(qv.x, w[0], acc[n]);
      acc[n] = fmaf(qv.y, w[1], acc[n]);
      acc[n] = fmaf(qv.z, w[2], acc[n]);
      acc[n] = fmaf(qv.w, w[3], acc[n]);
    }
  }
  #pragma unroll
  for (int n = 0; n < 8; ++n) {
    const float v = acc[n];
    h_lds[n][t] = v / (1.0f + expf(-v));
  }
  __syncthreads();

  // GEMM2: x = h@W2 + b2; thread t owns columns t, 128+t, 256+t
  float y0[8], y1[8], y2[8];
  {
    const float bb0 = b2[t], bb1 = b2[CC + t], bb2 = b2[2 * CC + t];
    #pragma unroll
    for (int n = 0; n < 8; ++n) { y0[n] = bb0; y1[n] = bb1; y2[n] = bb2; }
  }
  for (int k = 0; k < CC; k += 4) {
    float w0[4], w1[4], w2[4];
    #pragma unroll
    for (int r = 0; r < 4; ++r) {
      const size_t row = (size_t)(k + r) * TC;
      w0[r] = W2[row + t];
      w1[r] = W2[row + CC + t];
      w2[r] = W2[row + 2 * CC + t];
    }
    #pragma unroll
    for (int n = 0; n < 8; ++n) {
      const float4 hv = *reinterpret_cast<const float4*>(&h_lds[n][k]);
      y0[n] = fmaf(hv.x, w0[0], y0[n]); y0[n] = fmaf(hv.y, w0[1], y0[n]);
      y0[n] = fmaf(hv.z, w0[2], y0[n]); y0[n] = fmaf(hv.w, w0[3], y0[n]);
      y1[n] = fmaf(hv.x, w1[0], y1[n]); y1[n] = fmaf(hv.y, w1[1], y1[n]);
      y1[n] = fmaf(hv.z, w1[2], y1[n]); y1[n] = fmaf(hv.w, w1[3], y1[n]);
      y2[n] = fmaf(hv.x, w2[0], y2[n]); y2[n] = fmaf(hv.y, w2[1], y2[n]);
      y2[n] = fmaf(hv.z, w2[2], y2[n]); y2[n] = fmaf(hv.w, w2[3], y2[n]);
    }
  }
  #pragma unroll
  for (int n = 0; n < 8; ++n) {
    const size_t base = (size_t)(node0 + n) * TC;
    x[base + t]          = y0[n];
    x[base + CC + t]     = y1[n];
    x[base + 2 * CC + t] = y2[n];
  }
}

// ---------------------------------------------------------------------------
// Edge kernel: Wij = (attrs@W_filter + b_filter)*fcut; xj = x[j]*Wij;
// scatter-add dq into qout, dmu into muout via atomics.
// W_filter staged in LDS (30 KB); 8 edges per block.
// ---------------------------------------------------------------------------
#define EPB 8
__global__ __launch_bounds__(128) void edge_kernel(
    const int* __restrict__ eidx, const float* __restrict__ ew,
    const float* __restrict__ evers, const float* __restrict__ eattr,
    const float* __restrict__ Wf, const float* __restrict__ bf,
    const float* __restrict__ x, const float* __restrict__ mu_in,
    float* __restrict__ qout, float* __restrict__ muout) {
  __shared__ __align__(16) float wf_lds[BB * TC];   // 30720 B
  __shared__ float bf_lds[TC];
  __shared__ float attrs[BB];
  __shared__ float vers[3];
  __shared__ float fcut_s;

  const int t = threadIdx.x;
  for (int idx = t; idx < BB * TC; idx += 128) wf_lds[idx] = Wf[idx];
  for (int idx = t; idx < TC; idx += 128) bf_lds[idx] = bf[idx];

  const int e0 = blockIdx.x * EPB;
  for (int ei = 0; ei < EPB; ++ei) {
    const int e = e0 + ei;
    if (t < BB) attrs[t] = eattr[(size_t)e * BB + t];
    if (t >= 32 && t < 35) vers[t - 32] = evers[(size_t)e * 3 + (t - 32)];
    if (t == 35) {
      const float w = ew[e];
      const float f = 0.5f * (cosf(PI_F * w / RCUT_F) + 1.0f);
      fcut_s = (w < RCUT_F) ? f : 0.0f;
    }
    __syncthreads();

    const int i = eidx[e];
    const int j = eidx[NEDGES + e];

    float w0 = bf_lds[t], w1 = bf_lds[CC + t], w2 = bf_lds[2 * CC + t];
    #pragma unroll
    for (int b = 0; b < BB; ++b) {
      const float a = attrs[b];
      w0 = fmaf(a, wf_lds[b * TC + t], w0);
      w1 = fmaf(a, wf_lds[b * TC + CC + t], w1);
      w2 = fmaf(a, wf_lds[b * TC + 2 * CC + t], w2);
    }
    const float fc = fcut_s;
    w0 *= fc; w1 *= fc; w2 *= fc;

    const float* xj = x + (size_t)j * TC;
    const float dq    = xj[t] * w0;
    const float dmuR  = xj[CC + t] * w1;
    const float dmumu = xj[2 * CC + t] * w2;

    atomicAdd(qout + (size_t)i * CC + t, dq);

    const float* muj = mu_in + (size_t)j * TC;
    const float v0 = vers[0], v1 = vers[1], v2 = vers[2];
    atomicAdd(muout + (size_t)i * TC + t,          fmaf(dmuR, v0, dmumu * muj[t]));
    atomicAdd(muout + (size_t)i * TC + CC + t,     fmaf(dmuR, v1, dmumu * muj[CC + t]));
    atomicAdd(muout + (size_t)i * TC + 2 * CC + t, fmaf(dmuR, v2, dmumu * muj[2 * CC + t]));
    __syncthreads();
  }
}

// ---------------------------------------------------------------------------
// Mixing kernel: per-node, reads/writes updated q,mu in d_out in place.
// 8 nodes per block, 128 threads.
// ---------------------------------------------------------------------------
#define NPB 8
__global__ __launch_bounds__(128) void mix_kernel(
    const float* __restrict__ Wmix, const float* __restrict__ Wm1,
    const float* __restrict__ bm1, const float* __restrict__ Wm2,
    const float* __restrict__ bm2, float* __restrict__ qout,
    float* __restrict__ muout) {
  __shared__ __align__(16) float mu_lds[NPB][3][CC];   // 12 KB (updated mu)
  __shared__ __align__(16) float ctx_lds[NPB][2 * CC]; // 8 KB  [qnew, mu_Vn]
  __shared__ __align__(16) float h2_lds[NPB][CC];      // 4 KB

  const int t = threadIdx.x;
  const int node0 = blockIdx.x * NPB;

  #pragma unroll
  for (int n = 0; n < NPB; ++n) {
    const size_t mb = (size_t)(node0 + n) * TC;
    mu_lds[n][0][t] = muout[mb + t];
    mu_lds[n][1][t] = muout[mb + CC + t];
    mu_lds[n][2][t] = muout[mb + 2 * CC + t];
    ctx_lds[n][t] = qout[(size_t)(node0 + n) * CC + t];
  }
  __syncthreads();

  // mu_mix: thread t owns output columns t (mu_V) and 128+t (mu_W)
  float mV[NPB][3], mW[NPB][3];
  #pragma unroll
  for (int n = 0; n < NPB; ++n)
    #pragma unroll
    for (int v = 0; v < 3; ++v) { mV[n][v] = 0.0f; mW[n][v] = 0.0f; }

  for (int c = 0; c < CC; c += 4) {
    float wv[4], ww[4];
    #pragma unroll
    for (int r = 0; r < 4; ++r) {
      const size_t row = (size_t)(c + r) * (2 * CC);
      wv[r] = Wmix[row + t];
      ww[r] = Wmix[row + CC + t];
    }
    #pragma unroll
    for (int n = 0; n < NPB; ++n) {
      #pragma unroll
      for (int v = 0; v < 3; ++v) {
        const float4 m = *reinterpret_cast<const float4*>(&mu_lds[n][v][c]);
        float a = mV[n][v], b = mW[n][v];
        a = fmaf(m.x, wv[0], a); a = fmaf(m.y, wv[1], a);
        a = fmaf(m.z, wv[2], a); a = fmaf(m.w, wv[3], a);
        b = fmaf(m.x, ww[0], b); b = fmaf(m.y, ww[1], b);
        b = fmaf(m.z, ww[2], b); b = fmaf(m.w, ww[3], b);
        mV[n][v] = a; mW[n][v] = b;
      }
    }
  }
  #pragma unroll
  for (int n = 0; n < NPB; ++n) {
    const float ss = mV[n][0] * mV[n][0] + mV[n][1] * mV[n][1] + mV[n][2] * mV[n][2];
    ctx_lds[n][CC + t] = sqrtf(ss + 1e-8f);
  }
  __syncthreads();

  // h2 = silu(ctx @ Wm1 + bm1)
  float acc[NPB];
  {
    const float bv = bm1[t];
    #pragma unroll
    for (int n = 0; n < NPB; ++n) acc[n] = bv;
  }
  for (int k = 0; k < 2 * CC; k += 4) {
    float w[4];
    #pragma unroll
    for (int r = 0; r < 4; ++r) w[r] = Wm1[(size_t)(k + r) * CC + t];
    #pragma unroll
    for (int n = 0; n < NPB; ++n) {
      const float4 cx = *reinterpret_cast<const float4*>(&ctx_lds[n][k]);
      acc[n] = fmaf(cx.x, w[0], acc[n]); acc[n] = fmaf(cx.y, w[1], acc[n]);
      acc[n] = fmaf(cx.z, w[2], acc[n]); acc[n] = fmaf(cx.w, w[3], acc[n]);
    }
  }
  #pragma unroll
  for (int n = 0; n < NPB; ++n) {
    const float v = acc[n];
    h2_lds[n][t] = v / (1.0f + expf(-v));
  }
  __syncthreads();

  // y = h2 @ Wm2 + bm2; thread t owns columns t, 128+t, 256+t
  float y0[NPB], y1[NPB], y2[NPB];
  {
    const float bb0 = bm2[t], bb1 = bm2[CC + t], bb2 = bm2[2 * CC + t];
    #pragma unroll
    for (int n = 0; n < NPB; ++n) { y0[n] = bb0; y1[n] = bb1; y2[n] = bb2; }
  }
  for (int k = 0; k < CC; k += 4) {
    float w0[4], w1[4], w2[4];
    #pragma unroll
    for (int r = 0; r < 4; ++r) {
      const size_t row = (size_t)(k + r) * TC;
      w0[r] = Wm2[row + t];
      w1[r] = Wm2[row + CC + t];
      w2[r] = Wm2[row + 2 * CC + t];
    }
    #pragma unroll
    for (int n = 0; n < NPB; ++n) {
      const float4 h = *reinterpret_cast<const float4*>(&h2_lds[n][k]);
      y0[n] = fmaf(h.x, w0[0], y0[n]); y0[n] = fmaf(h.y, w0[1], y0[n]);
      y0[n] = fmaf(h.z, w0[2], y0[n]); y0[n] = fmaf(h.w, w0[3], y0[n]);
      y1[n] = fmaf(h.x, w1[0], y1[n]); y1[n] = fmaf(h.y, w1[1], y1[n]);
      y1[n] = fmaf(h.z, w1[2], y1[n]); y1[n] = fmaf(h.w, w1[3], y1[n]);
      y2[n] = fmaf(h.x, w2[0], y2[n]); y2[n] = fmaf(h.y, w2[1], y2[n]);
      y2[n] = fmaf(h.z, w2[2], y2[n]); y2[n] = fmaf(h.w, w2[3], y2[n]);
    }
  }

  // epilogue: q_out = qnew + y0 + y2 * <mu_V, mu_W>;  mu_out = munew + y1 * mu_W
  #pragma unroll
  for (int n = 0; n < NPB; ++n) {
    const float s = mV[n][0] * mW[n][0] + mV[n][1] * mW[n][1] + mV[n][2] * mW[n][2];
    const float qnew = ctx_lds[n][t];
    qout[(size_t)(node0 + n) * CC + t] = qnew + y0[n] + y2[n] * s;
    const size_t mb = (size_t)(node0 + n) * TC;
    muout[mb + t]          = mu_lds[n][0][t] + y1[n] * mW[n][0];
    muout[mb + CC + t]     = mu_lds[n][1][t] + y1[n] * mW[n][1];
    muout[mb + 2 * CC + t] = mu_lds[n][2][t] + y1[n] * mW[n][2];
  }
}

// ---------------------------------------------------------------------------
extern "C" void kernel_launch(void* const* d_in, const int* in_sizes, int n_in,
                              void* d_out, int out_size, void* d_ws, size_t ws_size,
                              hipStream_t stream) {
  const float* q     = (const float*)d_in[0];
  const float* mu    = (const float*)d_in[1];
  const int*   eidx  = (const int*)d_in[2];
  const float* ew    = (const float*)d_in[3];
  const float* evers = (const float*)d_in[4];
  const float* eattr = (const float*)d_in[5];
  const float* Wf    = (const float*)d_in[6];
  const float* bf    = (const float*)d_in[7];
  const float* W1    = (const float*)d_in[8];
  const float* b1    = (const float*)d_in[9];
  const float* W2    = (const float*)d_in[10];
  const float* b2    = (const float*)d_in[11];
  const float* Wmix  = (const float*)d_in[12];
  const float* Wm1   = (const float*)d_in[13];
  const float* bm1   = (const float*)d_in[14];
  const float* Wm2   = (const float*)d_in[15];
  const float* bm2   = (const float*)d_in[16];

  float* out   = (float*)d_out;
  float* qout  = out;                                // [N, C]
  float* muout = out + (size_t)NNODES * CC;          // [N, 3, C]
  float* x     = (float*)d_ws;                       // [N, 3C] = 30.72 MB

  // 1) init accumulators in d_out with q / mu
  {
    const size_t total4 = ((size_t)NNODES * CC + (size_t)NNODES * TC) / 4;
    const int blocks = (int)((total4 + 255) / 256);
    init_out_kernel<<<blocks, 256, 0, stream>>>(
        (const float4*)q, (const float4*)mu, (float4*)out);
  }
  // 2) context net -> x
  ctx_net_kernel<<<NNODES / 8, 128, 0, stream>>>(q, W1, b1, W2, b2, x);
  // 3) edge scatter
  edge_kernel<<<NEDGES / EPB, 128, 0, stream>>>(eidx, ew, evers, eattr,
                                                Wf, bf, x, mu, qout, muout);
  // 4) mixing (in place on d_out)
  mix_kernel<<<NNODES / NPB, 128, 0, stream>>>(Wmix, Wm1, bm1, Wm2, bm2,
                                               qout, muout);
}

// Round 2
// 905.191 us; speedup vs baseline: 1.5242x; 1.5242x over previous
//
#include <hip/hip_runtime.h>
#include <math.h>

#define NNODES 20000
#define NEDGES 320000
#define CC 128          // channels
#define TC 384          // 3*C
#define BB 20           // basis dim
#define RCUT_F 5.0f
#define PI_F 3.14159265358979323846f

// ---------------------------------------------------------------------------
// CSR build: zero -> histogram -> single-block scan -> scatter
// ---------------------------------------------------------------------------
__global__ __launch_bounds__(256) void zero_counts_kernel(int* __restrict__ counts) {
  const int i = blockIdx.x * 256 + threadIdx.x;
  if (i < NNODES) counts[i] = 0;
}

__global__ __launch_bounds__(256) void hist_kernel(const int* __restrict__ eidx,
                                                   int* __restrict__ counts) {
  const int e = blockIdx.x * 256 + threadIdx.x;
  if (e < NEDGES) atomicAdd(&counts[eidx[e]], 1);
}

__global__ __launch_bounds__(512) void scan_kernel(int* __restrict__ counts,
                                                   int* __restrict__ offsets) {
  __shared__ int sums[512];
  const int t = threadIdx.x;
  const int chunk = 40;                       // ceil(20000/512)
  const int lo = t * chunk;
  const int hi = min(lo + chunk, NNODES);
  int s = 0;
  for (int i = lo; i < hi; ++i) s += counts[i];
  sums[t] = s;
  __syncthreads();
  for (int d = 1; d < 512; d <<= 1) {
    const int other = (t >= d) ? sums[t - d] : 0;
    __syncthreads();
    sums[t] += other;
    __syncthreads();
  }
  int run = sums[t] - s;                      // exclusive prefix
  for (int i = lo; i < hi; ++i) {
    offsets[i] = run;
    run += counts[i];
    counts[i] = 0;                            // re-zero: reused as scatter cursor
  }
  if (hi == NNODES) offsets[NNODES] = run;    // == NEDGES
}

__global__ __launch_bounds__(256) void scatter_kernel(const int* __restrict__ eidx,
                                                      const int* __restrict__ offsets,
                                                      int* __restrict__ counts,
                                                      int* __restrict__ edge_list) {
  const int e = blockIdx.x * 256 + threadIdx.x;
  if (e < NEDGES) {
    const int i = eidx[e];
    const int pos = offsets[i] + atomicAdd(&counts[i], 1);
    edge_list[pos] = e;
  }
}

// ---------------------------------------------------------------------------
// Context net: x = silu(q@W1 + b1) @ W2 + b2      [N, 3C]
// 8 nodes per block, 128 threads.
// ---------------------------------------------------------------------------
__global__ __launch_bounds__(128) void ctx_net_kernel(
    const float* __restrict__ q,
    const float* __restrict__ W1, const float* __restrict__ b1,
    const float* __restrict__ W2, const float* __restrict__ b2,
    float* __restrict__ x) {
  __shared__ __align__(16) float q_lds[8][CC];
  __shared__ __align__(16) float h_lds[8][CC];
  const int t = threadIdx.x;
  const int node0 = blockIdx.x * 8;

  #pragma unroll
  for (int n = 0; n < 8; ++n)
    q_lds[n][t] = q[(size_t)(node0 + n) * CC + t];
  __syncthreads();

  float acc[8];
  {
    const float bv = b1[t];
    #pragma unroll
    for (int n = 0; n < 8; ++n) acc[n] = bv;
  }
  for (int k = 0; k < CC; k += 4) {
    float w[4];
    #pragma unroll
    for (int r = 0; r < 4; ++r) w[r] = W1[(size_t)(k + r) * CC + t];
    #pragma unroll
    for (int n = 0; n < 8; ++n) {
      const float4 qv = *reinterpret_cast<const float4*>(&q_lds[n][k]);
      acc[n] = fmaf(qv.x, w[0], acc[n]);
      acc[n] = fmaf(qv.y, w[1], acc[n]);
      acc[n] = fmaf(qv.z, w[2], acc[n]);
      acc[n] = fmaf(qv.w, w[3], acc[n]);
    }
  }
  #pragma unroll
  for (int n = 0; n < 8; ++n) {
    const float v = acc[n];
    h_lds[n][t] = v / (1.0f + expf(-v));
  }
  __syncthreads();

  float y0[8], y1[8], y2[8];
  {
    const float bb0 = b2[t], bb1 = b2[CC + t], bb2 = b2[2 * CC + t];
    #pragma unroll
    for (int n = 0; n < 8; ++n) { y0[n] = bb0; y1[n] = bb1; y2[n] = bb2; }
  }
  for (int k = 0; k < CC; k += 4) {
    float w0[4], w1[4], w2[4];
    #pragma unroll
    for (int r = 0; r < 4; ++r) {
      const size_t row = (size_t)(k + r) * TC;
      w0[r] = W2[row + t];
      w1[r] = W2[row + CC + t];
      w2[r] = W2[row + 2 * CC + t];
    }
    #pragma unroll
    for (int n = 0; n < 8; ++n) {
      const float4 hv = *reinterpret_cast<const float4*>(&h_lds[n][k]);
      y0[n] = fmaf(hv.x, w0[0], y0[n]); y0[n] = fmaf(hv.y, w0[1], y0[n]);
      y0[n] = fmaf(hv.z, w0[2], y0[n]); y0[n] = fmaf(hv.w, w0[3], y0[n]);
      y1[n] = fmaf(hv.x, w1[0], y1[n]); y1[n] = fmaf(hv.y, w1[1], y1[n]);
      y1[n] = fmaf(hv.z, w1[2], y1[n]); y1[n] = fmaf(hv.w, w1[3], y1[n]);
      y2[n] = fmaf(hv.x, w2[0], y2[n]); y2[n] = fmaf(hv.y, w2[1], y2[n]);
      y2[n] = fmaf(hv.z, w2[2], y2[n]); y2[n] = fmaf(hv.w, w2[3], y2[n]);
    }
  }
  #pragma unroll
  for (int n = 0; n < 8; ++n) {
    const size_t base = (size_t)(node0 + n) * TC;
    x[base + t]          = y0[n];
    x[base + CC + t]     = y1[n];
    x[base + 2 * CC + t] = y2[n];
  }
}

// ---------------------------------------------------------------------------
// Gather kernel: one block per node i; 512 threads = 4 edge-lanes x 128 ch.
// Each lane walks every 4th incoming edge, accumulates in registers,
// LDS-reduce, single write of q+dq / mu+dmu. No atomics.
// ---------------------------------------------------------------------------
#define GT 512
#define LANES 4
__global__ __launch_bounds__(GT) void gather_kernel(
    const int* __restrict__ eidx, const float* __restrict__ ew,
    const float* __restrict__ evers, const float* __restrict__ eattr,
    const float* __restrict__ Wf, const float* __restrict__ bf,
    const float* __restrict__ x, const float* __restrict__ mu_in,
    const float* __restrict__ q_in,
    const int* __restrict__ offsets, const int* __restrict__ edge_list,
    float* __restrict__ qout, float* __restrict__ muout) {
  __shared__ __align__(16) float wf_lds[BB * TC];        // 30720 B
  __shared__ __align__(16) float red[LANES][4][CC];      // 8192 B
  const int tid = threadIdx.x;
  const int lane = tid >> 7;       // 0..3 (wave-uniform)
  const int t = tid & 127;         // channel
  const int i = blockIdx.x;

  for (int idx = tid; idx < BB * TC; idx += GT) wf_lds[idx] = Wf[idx];
  const float bf0 = bf[t], bf1 = bf[CC + t], bf2 = bf[2 * CC + t];
  __syncthreads();

  const int start = offsets[i];
  const int end = offsets[i + 1];

  float dq = 0.0f, dm0 = 0.0f, dm1 = 0.0f, dm2 = 0.0f;
  for (int k = start + lane; k < end; k += LANES) {
    const int e = edge_list[k];                 // wave-uniform
    const int j = eidx[NEDGES + e];             // sender (wave-uniform)
    const float w = ew[e];
    const float fc = (w < RCUT_F)
        ? 0.5f * (cosf(PI_F * (1.0f / RCUT_F) * w) + 1.0f) : 0.0f;
    const float v0 = evers[(size_t)e * 3];
    const float v1 = evers[(size_t)e * 3 + 1];
    const float v2 = evers[(size_t)e * 3 + 2];

    float w0 = bf0, w1 = bf1, w2 = bf2;
    const float* ae = eattr + (size_t)e * BB;
    #pragma unroll
    for (int b = 0; b < BB; ++b) {
      const float a = ae[b];
      w0 = fmaf(a, wf_lds[b * TC + t], w0);
      w1 = fmaf(a, wf_lds[b * TC + CC + t], w1);
      w2 = fmaf(a, wf_lds[b * TC + 2 * CC + t], w2);
    }
    w0 *= fc; w1 *= fc; w2 *= fc;

    const float* xj = x + (size_t)j * TC;
    const float* muj = mu_in + (size_t)j * TC;
    dq = fmaf(xj[t], w0, dq);
    const float dmuR = xj[CC + t] * w1;
    const float dmumu = xj[2 * CC + t] * w2;
    dm0 = fmaf(dmuR, v0, fmaf(dmumu, muj[t], dm0));
    dm1 = fmaf(dmuR, v1, fmaf(dmumu, muj[CC + t], dm1));
    dm2 = fmaf(dmuR, v2, fmaf(dmumu, muj[2 * CC + t], dm2));
  }
  red[lane][0][t] = dq;
  red[lane][1][t] = dm0;
  red[lane][2][t] = dm1;
  red[lane][3][t] = dm2;
  __syncthreads();

  // lane c sums component c across the 4 lanes and writes it
  const float a = red[0][lane][t] + red[1][lane][t] +
                  red[2][lane][t] + red[3][lane][t];
  if (lane == 0) {
    qout[(size_t)i * CC + t] = q_in[(size_t)i * CC + t] + a;
  } else {
    const int v = lane - 1;
    muout[(size_t)i * TC + v * CC + t] =
        mu_in[(size_t)i * TC + v * CC + t] + a;
  }
}

// ---------------------------------------------------------------------------
// Mixing kernel: per-node, reads/writes updated q,mu in d_out in place.
// 8 nodes per block, 128 threads.
// ---------------------------------------------------------------------------
#define NPB 8
__global__ __launch_bounds__(128) void mix_kernel(
    const float* __restrict__ Wmix, const float* __restrict__ Wm1,
    const float* __restrict__ bm1, const float* __restrict__ Wm2,
    const float* __restrict__ bm2, float* __restrict__ qout,
    float* __restrict__ muout) {
  __shared__ __align__(16) float mu_lds[NPB][3][CC];
  __shared__ __align__(16) float ctx_lds[NPB][2 * CC];
  __shared__ __align__(16) float h2_lds[NPB][CC];

  const int t = threadIdx.x;
  const int node0 = blockIdx.x * NPB;

  #pragma unroll
  for (int n = 0; n < NPB; ++n) {
    const size_t mb = (size_t)(node0 + n) * TC;
    mu_lds[n][0][t] = muout[mb + t];
    mu_lds[n][1][t] = muout[mb + CC + t];
    mu_lds[n][2][t] = muout[mb + 2 * CC + t];
    ctx_lds[n][t] = qout[(size_t)(node0 + n) * CC + t];
  }
  __syncthreads();

  float mV[NPB][3], mW[NPB][3];
  #pragma unroll
  for (int n = 0; n < NPB; ++n)
    #pragma unroll
    for (int v = 0; v < 3; ++v) { mV[n][v] = 0.0f; mW[n][v] = 0.0f; }

  for (int c = 0; c < CC; c += 4) {
    float wv[4], ww[4];
    #pragma unroll
    for (int r = 0; r < 4; ++r) {
      const size_t row = (size_t)(c + r) * (2 * CC);
      wv[r] = Wmix[row + t];
      ww[r] = Wmix[row + CC + t];
    }
    #pragma unroll
    for (int n = 0; n < NPB; ++n) {
      #pragma unroll
      for (int v = 0; v < 3; ++v) {
        const float4 m = *reinterpret_cast<const float4*>(&mu_lds[n][v][c]);
        float a = mV[n][v], b = mW[n][v];
        a = fmaf(m.x, wv[0], a); a = fmaf(m.y, wv[1], a);
        a = fmaf(m.z, wv[2], a); a = fmaf(m.w, wv[3], a);
        b = fmaf(m.x, ww[0], b); b = fmaf(m.y, ww[1], b);
        b = fmaf(m.z, ww[2], b); b = fmaf(m.w, ww[3], b);
        mV[n][v] = a; mW[n][v] = b;
      }
    }
  }
  #pragma unroll
  for (int n = 0; n < NPB; ++n) {
    const float ss = mV[n][0] * mV[n][0] + mV[n][1] * mV[n][1] + mV[n][2] * mV[n][2];
    ctx_lds[n][CC + t] = sqrtf(ss + 1e-8f);
  }
  __syncthreads();

  float acc[NPB];
  {
    const float bv = bm1[t];
    #pragma unroll
    for (int n = 0; n < NPB; ++n) acc[n] = bv;
  }
  for (int k = 0; k < 2 * CC; k += 4) {
    float w[4];
    #pragma unroll
    for (int r = 0; r < 4; ++r) w[r] = Wm1[(size_t)(k + r) * CC + t];
    #pragma unroll
    for (int n = 0; n < NPB; ++n) {
      const float4 cx = *reinterpret_cast<const float4*>(&ctx_lds[n][k]);
      acc[n] = fmaf(cx.x, w[0], acc[n]); acc[n] = fmaf(cx.y, w[1], acc[n]);
      acc[n] = fmaf(cx.z, w[2], acc[n]); acc[n] = fmaf(cx.w, w[3], acc[n]);
    }
  }
  #pragma unroll
  for (int n = 0; n < NPB; ++n) {
    const float v = acc[n];
    h2_lds[n][t] = v / (1.0f + expf(-v));
  }
  __syncthreads();

  float y0[NPB], y1[NPB], y2[NPB];
  {
    const float bb0 = bm2[t], bb1 = bm2[CC + t], bb2 = bm2[2 * CC + t];
    #pragma unroll
    for (int n = 0; n < NPB; ++n) { y0[n] = bb0; y1[n] = bb1; y2[n] = bb2; }
  }
  for (int k = 0; k < CC; k += 4) {
    float w0[4], w1[4], w2[4];
    #pragma unroll
    for (int r = 0; r < 4; ++r) {
      const size_t row = (size_t)(k + r) * TC;
      w0[r] = Wm2[row + t];
      w1[r] = Wm2[row + CC + t];
      w2[r] = Wm2[row + 2 * CC + t];
    }
    #pragma unroll
    for (int n = 0; n < NPB; ++n) {
      const float4 h = *reinterpret_cast<const float4*>(&h2_lds[n][k]);
      y0[n] = fmaf(h.x, w0[0], y0[n]); y0[n] = fmaf(h.y, w0[1], y0[n]);
      y0[n] = fmaf(h.z, w0[2], y0[n]); y0[n] = fmaf(h.w, w0[3], y0[n]);
      y1[n] = fmaf(h.x, w1[0], y1[n]); y1[n] = fmaf(h.y, w1[1], y1[n]);
      y1[n] = fmaf(h.z, w1[2], y1[n]); y1[n] = fmaf(h.w, w1[3], y1[n]);
      y2[n] = fmaf(h.x, w2[0], y2[n]); y2[n] = fmaf(h.y, w2[1], y2[n]);
      y2[n] = fmaf(h.z, w2[2], y2[n]); y2[n] = fmaf(h.w, w2[3], y2[n]);
    }
  }

  #pragma unroll
  for (int n = 0; n < NPB; ++n) {
    const float s = mV[n][0] * mW[n][0] + mV[n][1] * mW[n][1] + mV[n][2] * mW[n][2];
    const float qnew = ctx_lds[n][t];
    qout[(size_t)(node0 + n) * CC + t] = qnew + y0[n] + y2[n] * s;
    const size_t mb = (size_t)(node0 + n) * TC;
    muout[mb + t]          = mu_lds[n][0][t] + y1[n] * mW[n][0];
    muout[mb + CC + t]     = mu_lds[n][1][t] + y1[n] * mW[n][1];
    muout[mb + 2 * CC + t] = mu_lds[n][2][t] + y1[n] * mW[n][2];
  }
}

// ---------------------------------------------------------------------------
extern "C" void kernel_launch(void* const* d_in, const int* in_sizes, int n_in,
                              void* d_out, int out_size, void* d_ws, size_t ws_size,
                              hipStream_t stream) {
  const float* q     = (const float*)d_in[0];
  const float* mu    = (const float*)d_in[1];
  const int*   eidx  = (const int*)d_in[2];
  const float* ew    = (const float*)d_in[3];
  const float* evers = (const float*)d_in[4];
  const float* eattr = (const float*)d_in[5];
  const float* Wf    = (const float*)d_in[6];
  const float* bf    = (const float*)d_in[7];
  const float* W1    = (const float*)d_in[8];
  const float* b1    = (const float*)d_in[9];
  const float* W2    = (const float*)d_in[10];
  const float* b2    = (const float*)d_in[11];
  const float* Wmix  = (const float*)d_in[12];
  const float* Wm1   = (const float*)d_in[13];
  const float* bm1   = (const float*)d_in[14];
  const float* Wm2   = (const float*)d_in[15];
  const float* bm2   = (const float*)d_in[16];

  float* out   = (float*)d_out;
  float* qout  = out;                                // [N, C]
  float* muout = out + (size_t)NNODES * CC;          // [N, 3, C]

  // workspace layout
  float* x        = (float*)d_ws;                    // [N, 3C] floats
  int*   counts   = (int*)(x + (size_t)NNODES * TC); // [N]
  int*   offsets  = counts + NNODES;                 // [N+1]
  int*   edge_list= offsets + NNODES + 1;            // [E]

  // CSR build (by receiver idx_i)
  zero_counts_kernel<<<(NNODES + 255) / 256, 256, 0, stream>>>(counts);
  hist_kernel<<<(NEDGES + 255) / 256, 256, 0, stream>>>(eidx, counts);
  scan_kernel<<<1, 512, 0, stream>>>(counts, offsets);
  scatter_kernel<<<(NEDGES + 255) / 256, 256, 0, stream>>>(eidx, offsets,
                                                           counts, edge_list);
  // context net -> x
  ctx_net_kernel<<<NNODES / 8, 128, 0, stream>>>(q, W1, b1, W2, b2, x);
  // per-node gather (atomic-free scatter replacement), writes q+dq / mu+dmu
  gather_kernel<<<NNODES, GT, 0, stream>>>(eidx, ew, evers, eattr, Wf, bf,
                                           x, mu, q, offsets, edge_list,
                                           qout, muout);
  // mixing (in place on d_out)
  mix_kernel<<<NNODES / NPB, 128, 0, stream>>>(Wmix, Wm1, bm1, Wm2, bm2,
                                               qout, muout);
}

// Round 3
// 863.923 us; speedup vs baseline: 1.5971x; 1.0478x over previous
//
#include <hip/hip_runtime.h>
#include <math.h>

#define NNODES 20000
#define NEDGES 320000
#define CC 128          // channels
#define TC 384          // 3*C
#define BB 20           // basis dim
#define RCUT_F 5.0f
#define PI_F 3.14159265358979323846f

// ---------------------------------------------------------------------------
// CSR build: zero -> histogram -> single-block scan -> scatter
// ---------------------------------------------------------------------------
__global__ __launch_bounds__(256) void zero_counts_kernel(int* __restrict__ counts) {
  const int i = blockIdx.x * 256 + threadIdx.x;
  if (i < NNODES) counts[i] = 0;
}

__global__ __launch_bounds__(256) void hist_kernel(const int* __restrict__ eidx,
                                                   int* __restrict__ counts) {
  const int e = blockIdx.x * 256 + threadIdx.x;
  if (e < NEDGES) atomicAdd(&counts[eidx[e]], 1);
}

__global__ __launch_bounds__(512) void scan_kernel(int* __restrict__ counts,
                                                   int* __restrict__ offsets) {
  __shared__ int sums[512];
  const int t = threadIdx.x;
  const int chunk = 40;                       // ceil(20000/512)
  const int lo = t * chunk;
  const int hi = min(lo + chunk, NNODES);
  int s = 0;
  for (int i = lo; i < hi; ++i) s += counts[i];
  sums[t] = s;
  __syncthreads();
  for (int d = 1; d < 512; d <<= 1) {
    const int other = (t >= d) ? sums[t - d] : 0;
    __syncthreads();
    sums[t] += other;
    __syncthreads();
  }
  int run = sums[t] - s;                      // exclusive prefix
  for (int i = lo; i < hi; ++i) {
    offsets[i] = run;
    run += counts[i];
    counts[i] = 0;                            // re-zero: reused as scatter cursor
  }
  if (hi == NNODES) offsets[NNODES] = run;    // == NEDGES
}

__global__ __launch_bounds__(256) void scatter_kernel(const int* __restrict__ eidx,
                                                      const int* __restrict__ offsets,
                                                      int* __restrict__ counts,
                                                      int* __restrict__ edge_list) {
  const int e = blockIdx.x * 256 + threadIdx.x;
  if (e < NEDGES) {
    const int i = eidx[e];
    const int pos = offsets[i] + atomicAdd(&counts[i], 1);
    edge_list[pos] = e;
  }
}

// ---------------------------------------------------------------------------
// Context net: x = silu(q@W1 + b1) @ W2 + b2      [N, 3C]
// 8 nodes per block, 128 threads.
// ---------------------------------------------------------------------------
__global__ __launch_bounds__(128) void ctx_net_kernel(
    const float* __restrict__ q,
    const float* __restrict__ W1, const float* __restrict__ b1,
    const float* __restrict__ W2, const float* __restrict__ b2,
    float* __restrict__ x) {
  __shared__ __align__(16) float q_lds[8][CC];
  __shared__ __align__(16) float h_lds[8][CC];
  const int t = threadIdx.x;
  const int node0 = blockIdx.x * 8;

  #pragma unroll
  for (int n = 0; n < 8; ++n)
    q_lds[n][t] = q[(size_t)(node0 + n) * CC + t];
  __syncthreads();

  float acc[8];
  {
    const float bv = b1[t];
    #pragma unroll
    for (int n = 0; n < 8; ++n) acc[n] = bv;
  }
  for (int k = 0; k < CC; k += 4) {
    float w[4];
    #pragma unroll
    for (int r = 0; r < 4; ++r) w[r] = W1[(size_t)(k + r) * CC + t];
    #pragma unroll
    for (int n = 0; n < 8; ++n) {
      const float4 qv = *reinterpret_cast<const float4*>(&q_lds[n][k]);
      acc[n] = fmaf(qv.x, w[0], acc[n]);
      acc[n] = fmaf(qv.y, w[1], acc[n]);
      acc[n] = fmaf(qv.z, w[2], acc[n]);
      acc[n] = fmaf(qv.w, w[3], acc[n]);
    }
  }
  #pragma unroll
  for (int n = 0; n < 8; ++n) {
    const float v = acc[n];
    h_lds[n][t] = v / (1.0f + expf(-v));
  }
  __syncthreads();

  float y0[8], y1[8], y2[8];
  {
    const float bb0 = b2[t], bb1 = b2[CC + t], bb2 = b2[2 * CC + t];
    #pragma unroll
    for (int n = 0; n < 8; ++n) { y0[n] = bb0; y1[n] = bb1; y2[n] = bb2; }
  }
  for (int k = 0; k < CC; k += 4) {
    float w0[4], w1[4], w2[4];
    #pragma unroll
    for (int r = 0; r < 4; ++r) {
      const size_t row = (size_t)(k + r) * TC;
      w0[r] = W2[row + t];
      w1[r] = W2[row + CC + t];
      w2[r] = W2[row + 2 * CC + t];
    }
    #pragma unroll
    for (int n = 0; n < 8; ++n) {
      const float4 hv = *reinterpret_cast<const float4*>(&h_lds[n][k]);
      y0[n] = fmaf(hv.x, w0[0], y0[n]); y0[n] = fmaf(hv.y, w0[1], y0[n]);
      y0[n] = fmaf(hv.z, w0[2], y0[n]); y0[n] = fmaf(hv.w, w0[3], y0[n]);
      y1[n] = fmaf(hv.x, w1[0], y1[n]); y1[n] = fmaf(hv.y, w1[1], y1[n]);
      y1[n] = fmaf(hv.z, w1[2], y1[n]); y1[n] = fmaf(hv.w, w1[3], y1[n]);
      y2[n] = fmaf(hv.x, w2[0], y2[n]); y2[n] = fmaf(hv.y, w2[1], y2[n]);
      y2[n] = fmaf(hv.z, w2[2], y2[n]); y2[n] = fmaf(hv.w, w2[3], y2[n]);
    }
  }
  #pragma unroll
  for (int n = 0; n < 8; ++n) {
    const size_t base = (size_t)(node0 + n) * TC;
    x[base + t]          = y0[n];
    x[base + CC + t]     = y1[n];
    x[base + 2 * CC + t] = y2[n];
  }
}

// ---------------------------------------------------------------------------
// Gather kernel: one block of 384 threads per node i; thread c owns filter
// output column c. Filter weights Wf[:,c] live in 20 REGISTERS (no LDS reads
// in the edge loop). Per edge: broadcast edge scalars, 21 fma filter, one
// coalesced x[j] row read, group-specific accumulate:
//   c in [0,128):    dq        += xj*w
//   c in [128,256):  accR[v]   += (xj*w) * versor[v]
//   c in [256,384):  accM[v]   += (xj*w) * mu[j][v][ch]
// Final: dmu[v][ch] = accR[v][ch] + accM[v][ch]  (combined via 1.5 KB LDS).
// ---------------------------------------------------------------------------
#define GTH 384
__global__ __launch_bounds__(GTH) void gather_kernel(
    const int* __restrict__ eidx, const float* __restrict__ ew,
    const float* __restrict__ evers, const float* __restrict__ eattr,
    const float* __restrict__ Wf, const float* __restrict__ bf,
    const float* __restrict__ x, const float* __restrict__ mu_in,
    const float* __restrict__ q_in,
    const int* __restrict__ offsets, const int* __restrict__ edge_list,
    float* __restrict__ qout, float* __restrict__ muout) {
  __shared__ float red[3][CC];     // dmuR-side partial, combined by grp 2

  const int c = threadIdx.x;       // 0..383: output column
  const int i = blockIdx.x;        // node
  const int grp = c >> 7;          // 0: dq, 1: dmuR, 2: dmumu (wave-uniform)
  const int ch = c & 127;

  // filter weights for column c -> registers (coalesced, once per block)
  float wreg[BB];
  #pragma unroll
  for (int b = 0; b < BB; ++b) wreg[b] = Wf[b * TC + c];
  const float bfc = bf[c];

  const int start = offsets[i];
  const int end = offsets[i + 1];

  float a0 = 0.0f, a1 = 0.0f, a2 = 0.0f;

  for (int k = start; k < end; ++k) {
    const int e = edge_list[k];                // broadcast
    const int j = eidx[NEDGES + e];            // sender (broadcast)
    const float w = ew[e];
    const float fc = (w < RCUT_F)
        ? 0.5f * (cosf(PI_F * (1.0f / RCUT_F) * w) + 1.0f) : 0.0f;

    // filter: wsum = fc * (attrs @ Wf[:,c] + bf[c]); attrs broadcast as float2
    const float2* ae2 = reinterpret_cast<const float2*>(eattr + (size_t)e * BB);
    float wsum = bfc;
    #pragma unroll
    for (int b = 0; b < BB / 2; ++b) {
      const float2 a = ae2[b];
      wsum = fmaf(a.x, wreg[2 * b], wsum);
      wsum = fmaf(a.y, wreg[2 * b + 1], wsum);
    }
    wsum *= fc;

    // one coalesced row read: all 384 threads read x[j][c]
    const float xv = x[(size_t)j * TC + c] * wsum;

    if (grp == 0) {
      a0 += xv;                                       // dq
    } else if (grp == 1) {
      const float v0 = evers[(size_t)e * 3];
      const float v1 = evers[(size_t)e * 3 + 1];
      const float v2 = evers[(size_t)e * 3 + 2];
      a0 = fmaf(xv, v0, a0);                          // dmuR * versor
      a1 = fmaf(xv, v1, a1);
      a2 = fmaf(xv, v2, a2);
    } else {
      const float* muj = mu_in + (size_t)j * TC + ch;
      a0 = fmaf(xv, muj[0], a0);                      // dmumu * mu[j]
      a1 = fmaf(xv, muj[CC], a1);
      a2 = fmaf(xv, muj[2 * CC], a2);
    }
  }

  if (grp == 1) { red[0][ch] = a0; red[1][ch] = a1; red[2][ch] = a2; }
  __syncthreads();

  if (grp == 0) {
    qout[(size_t)i * CC + ch] = q_in[(size_t)i * CC + ch] + a0;
  } else if (grp == 2) {
    const size_t mb = (size_t)i * TC;
    muout[mb + ch]          = mu_in[mb + ch]          + red[0][ch] + a0;
    muout[mb + CC + ch]     = mu_in[mb + CC + ch]     + red[1][ch] + a1;
    muout[mb + 2 * CC + ch] = mu_in[mb + 2 * CC + ch] + red[2][ch] + a2;
  }
}

// ---------------------------------------------------------------------------
// Mixing kernel: per-node, reads/writes updated q,mu in d_out in place.
// 8 nodes per block, 128 threads.
// ---------------------------------------------------------------------------
#define NPB 8
__global__ __launch_bounds__(128) void mix_kernel(
    const float* __restrict__ Wmix, const float* __restrict__ Wm1,
    const float* __restrict__ bm1, const float* __restrict__ Wm2,
    const float* __restrict__ bm2, float* __restrict__ qout,
    float* __restrict__ muout) {
  __shared__ __align__(16) float mu_lds[NPB][3][CC];
  __shared__ __align__(16) float ctx_lds[NPB][2 * CC];
  __shared__ __align__(16) float h2_lds[NPB][CC];

  const int t = threadIdx.x;
  const int node0 = blockIdx.x * NPB;

  #pragma unroll
  for (int n = 0; n < NPB; ++n) {
    const size_t mb = (size_t)(node0 + n) * TC;
    mu_lds[n][0][t] = muout[mb + t];
    mu_lds[n][1][t] = muout[mb + CC + t];
    mu_lds[n][2][t] = muout[mb + 2 * CC + t];
    ctx_lds[n][t] = qout[(size_t)(node0 + n) * CC + t];
  }
  __syncthreads();

  float mV[NPB][3], mW[NPB][3];
  #pragma unroll
  for (int n = 0; n < NPB; ++n)
    #pragma unroll
    for (int v = 0; v < 3; ++v) { mV[n][v] = 0.0f; mW[n][v] = 0.0f; }

  for (int c = 0; c < CC; c += 4) {
    float wv[4], ww[4];
    #pragma unroll
    for (int r = 0; r < 4; ++r) {
      const size_t row = (size_t)(c + r) * (2 * CC);
      wv[r] = Wmix[row + t];
      ww[r] = Wmix[row + CC + t];
    }
    #pragma unroll
    for (int n = 0; n < NPB; ++n) {
      #pragma unroll
      for (int v = 0; v < 3; ++v) {
        const float4 m = *reinterpret_cast<const float4*>(&mu_lds[n][v][c]);
        float a = mV[n][v], b = mW[n][v];
        a = fmaf(m.x, wv[0], a); a = fmaf(m.y, wv[1], a);
        a = fmaf(m.z, wv[2], a); a = fmaf(m.w, wv[3], a);
        b = fmaf(m.x, ww[0], b); b = fmaf(m.y, ww[1], b);
        b = fmaf(m.z, ww[2], b); b = fmaf(m.w, ww[3], b);
        mV[n][v] = a; mW[n][v] = b;
      }
    }
  }
  #pragma unroll
  for (int n = 0; n < NPB; ++n) {
    const float ss = mV[n][0] * mV[n][0] + mV[n][1] * mV[n][1] + mV[n][2] * mV[n][2];
    ctx_lds[n][CC + t] = sqrtf(ss + 1e-8f);
  }
  __syncthreads();

  float acc[NPB];
  {
    const float bv = bm1[t];
    #pragma unroll
    for (int n = 0; n < NPB; ++n) acc[n] = bv;
  }
  for (int k = 0; k < 2 * CC; k += 4) {
    float w[4];
    #pragma unroll
    for (int r = 0; r < 4; ++r) w[r] = Wm1[(size_t)(k + r) * CC + t];
    #pragma unroll
    for (int n = 0; n < NPB; ++n) {
      const float4 cx = *reinterpret_cast<const float4*>(&ctx_lds[n][k]);
      acc[n] = fmaf(cx.x, w[0], acc[n]); acc[n] = fmaf(cx.y, w[1], acc[n]);
      acc[n] = fmaf(cx.z, w[2], acc[n]); acc[n] = fmaf(cx.w, w[3], acc[n]);
    }
  }
  #pragma unroll
  for (int n = 0; n < NPB; ++n) {
    const float v = acc[n];
    h2_lds[n][t] = v / (1.0f + expf(-v));
  }
  __syncthreads();

  float y0[NPB], y1[NPB], y2[NPB];
  {
    const float bb0 = bm2[t], bb1 = bm2[CC + t], bb2 = bm2[2 * CC + t];
    #pragma unroll
    for (int n = 0; n < NPB; ++n) { y0[n] = bb0; y1[n] = bb1; y2[n] = bb2; }
  }
  for (int k = 0; k < CC; k += 4) {
    float w0[4], w1[4], w2[4];
    #pragma unroll
    for (int r = 0; r < 4; ++r) {
      const size_t row = (size_t)(k + r) * TC;
      w0[r] = Wm2[row + t];
      w1[r] = Wm2[row + CC + t];
      w2[r] = Wm2[row + 2 * CC + t];
    }
    #pragma unroll
    for (int n = 0; n < NPB; ++n) {
      const float4 h = *reinterpret_cast<const float4*>(&h2_lds[n][k]);
      y0[n] = fmaf(h.x, w0[0], y0[n]); y0[n] = fmaf(h.y, w0[1], y0[n]);
      y0[n] = fmaf(h.z, w0[2], y0[n]); y0[n] = fmaf(h.w, w0[3], y0[n]);
      y1[n] = fmaf(h.x, w1[0], y1[n]); y1[n] = fmaf(h.y, w1[1], y1[n]);
      y1[n] = fmaf(h.z, w1[2], y1[n]); y1[n] = fmaf(h.w, w1[3], y1[n]);
      y2[n] = fmaf(h.x, w2[0], y2[n]); y2[n] = fmaf(h.y, w2[1], y2[n]);
      y2[n] = fmaf(h.z, w2[2], y2[n]); y2[n] = fmaf(h.w, w2[3], y2[n]);
    }
  }

  #pragma unroll
  for (int n = 0; n < NPB; ++n) {
    const float s = mV[n][0] * mW[n][0] + mV[n][1] * mW[n][1] + mV[n][2] * mW[n][2];
    const float qnew = ctx_lds[n][t];
    qout[(size_t)(node0 + n) * CC + t] = qnew + y0[n] + y2[n] * s;
    const size_t mb = (size_t)(node0 + n) * TC;
    muout[mb + t]          = mu_lds[n][0][t] + y1[n] * mW[n][0];
    muout[mb + CC + t]     = mu_lds[n][1][t] + y1[n] * mW[n][1];
    muout[mb + 2 * CC + t] = mu_lds[n][2][t] + y1[n] * mW[n][2];
  }
}

// ---------------------------------------------------------------------------
extern "C" void kernel_launch(void* const* d_in, const int* in_sizes, int n_in,
                              void* d_out, int out_size, void* d_ws, size_t ws_size,
                              hipStream_t stream) {
  const float* q     = (const float*)d_in[0];
  const float* mu    = (const float*)d_in[1];
  const int*   eidx  = (const int*)d_in[2];
  const float* ew    = (const float*)d_in[3];
  const float* evers = (const float*)d_in[4];
  const float* eattr = (const float*)d_in[5];
  const float* Wf    = (const float*)d_in[6];
  const float* bf    = (const float*)d_in[7];
  const float* W1    = (const float*)d_in[8];
  const float* b1    = (const float*)d_in[9];
  const float* W2    = (const float*)d_in[10];
  const float* b2    = (const float*)d_in[11];
  const float* Wmix  = (const float*)d_in[12];
  const float* Wm1   = (const float*)d_in[13];
  const float* bm1   = (const float*)d_in[14];
  const float* Wm2   = (const float*)d_in[15];
  const float* bm2   = (const float*)d_in[16];

  float* out   = (float*)d_out;
  float* qout  = out;                                // [N, C]
  float* muout = out + (size_t)NNODES * CC;          // [N, 3, C]

  // workspace layout (same footprint as round 1: ~32.2 MB)
  float* x        = (float*)d_ws;                    // [N, 3C] floats
  int*   counts   = (int*)(x + (size_t)NNODES * TC); // [N]
  int*   offsets  = counts + NNODES;                 // [N+1]
  int*   edge_list= offsets + NNODES + 1;            // [E]

  // CSR build (by receiver idx_i)
  zero_counts_kernel<<<(NNODES + 255) / 256, 256, 0, stream>>>(counts);
  hist_kernel<<<(NEDGES + 255) / 256, 256, 0, stream>>>(eidx, counts);
  scan_kernel<<<1, 512, 0, stream>>>(counts, offsets);
  scatter_kernel<<<(NEDGES + 255) / 256, 256, 0, stream>>>(eidx, offsets,
                                                           counts, edge_list);
  // context net -> x
  ctx_net_kernel<<<NNODES / 8, 128, 0, stream>>>(q, W1, b1, W2, b2, x);
  // per-node gather (register-resident filter weights, no LDS in hot loop)
  gather_kernel<<<NNODES, GTH, 0, stream>>>(eidx, ew, evers, eattr, Wf, bf,
                                            x, mu, q, offsets, edge_list,
                                            qout, muout);
  // mixing (in place on d_out)
  mix_kernel<<<NNODES / NPB, 128, 0, stream>>>(Wmix, Wm1, bm1, Wm2, bm2,
                                               qout, muout);
}

// Round 4
// 790.868 us; speedup vs baseline: 1.7446x; 1.0924x over previous
//
#include <hip/hip_runtime.h>
#include <math.h>

#define NNODES 20000
#define NEDGES 320000
#define CC 128          // channels
#define TC 384          // 3*C
#define BB 20           // basis dim
#define RCUT_F 5.0f
#define PI_F 3.14159265358979323846f
#define PKF 28          // packed floats per edge (112 B, float4-aligned)

// ---------------------------------------------------------------------------
// CSR build: zero -> histogram -> single-block scan -> pack+scatter
// ---------------------------------------------------------------------------
__global__ __launch_bounds__(256) void zero_counts_kernel(int* __restrict__ counts) {
  const int i = blockIdx.x * 256 + threadIdx.x;
  if (i < NNODES) counts[i] = 0;
}

__global__ __launch_bounds__(256) void hist_kernel(const int* __restrict__ eidx,
                                                   int* __restrict__ counts) {
  const int e = blockIdx.x * 256 + threadIdx.x;
  if (e < NEDGES) atomicAdd(&counts[eidx[e]], 1);
}

__global__ __launch_bounds__(512) void scan_kernel(int* __restrict__ counts,
                                                   int* __restrict__ offsets) {
  __shared__ int sums[512];
  const int t = threadIdx.x;
  const int chunk = 40;                       // ceil(20000/512)
  const int lo = t * chunk;
  const int hi = min(lo + chunk, NNODES);
  int s = 0;
  for (int i = lo; i < hi; ++i) s += counts[i];
  sums[t] = s;
  __syncthreads();
  for (int d = 1; d < 512; d <<= 1) {
    const int other = (t >= d) ? sums[t - d] : 0;
    __syncthreads();
    sums[t] += other;
    __syncthreads();
  }
  int run = sums[t] - s;                      // exclusive prefix
  for (int i = lo; i < hi; ++i) {
    offsets[i] = run;
    run += counts[i];
    counts[i] = 0;                            // re-zero: reused as scatter cursor
  }
  if (hi == NNODES) offsets[NNODES] = run;    // == NEDGES
}

// packed[pos] = { j(bits), fc, v0, v1, v2, fc*attrs[0..19], pad[3] }
__global__ __launch_bounds__(256) void pack_scatter_kernel(
    const int* __restrict__ eidx, const float* __restrict__ ew,
    const float* __restrict__ evers, const float* __restrict__ eattr,
    const int* __restrict__ offsets, int* __restrict__ counts,
    float* __restrict__ packed) {
  const int e = blockIdx.x * 256 + threadIdx.x;
  if (e >= NEDGES) return;
  const int i = eidx[e];
  const int j = eidx[NEDGES + e];
  const int pos = offsets[i] + atomicAdd(&counts[i], 1);
  const float w = ew[e];
  const float fc = (w < RCUT_F)
      ? 0.5f * (cosf(PI_F * (1.0f / RCUT_F) * w) + 1.0f) : 0.0f;
  float* p = packed + (size_t)pos * PKF;
  p[0] = __int_as_float(j);
  p[1] = fc;
  p[2] = evers[(size_t)e * 3];
  p[3] = evers[(size_t)e * 3 + 1];
  p[4] = evers[(size_t)e * 3 + 2];
  const float* ae = eattr + (size_t)e * BB;
  #pragma unroll
  for (int b = 0; b < BB; ++b) p[5 + b] = fc * ae[b];
}

// fallback (no packing) scatter for small ws
__global__ __launch_bounds__(256) void scatter_kernel(const int* __restrict__ eidx,
                                                      const int* __restrict__ offsets,
                                                      int* __restrict__ counts,
                                                      int* __restrict__ edge_list) {
  const int e = blockIdx.x * 256 + threadIdx.x;
  if (e < NEDGES) {
    const int i = eidx[e];
    const int pos = offsets[i] + atomicAdd(&counts[i], 1);
    edge_list[pos] = e;
  }
}

// ---------------------------------------------------------------------------
// Context net: x = silu(q@W1 + b1) @ W2 + b2      [N, 3C]
// 16 nodes per block, 128 threads (16 accumulators per weight load).
// ---------------------------------------------------------------------------
#define CNPB 16
__global__ __launch_bounds__(128) void ctx_net_kernel(
    const float* __restrict__ q,
    const float* __restrict__ W1, const float* __restrict__ b1,
    const float* __restrict__ W2, const float* __restrict__ b2,
    float* __restrict__ x) {
  __shared__ __align__(16) float q_lds[CNPB][CC];
  __shared__ __align__(16) float h_lds[CNPB][CC];
  const int t = threadIdx.x;
  const int node0 = blockIdx.x * CNPB;

  #pragma unroll
  for (int n = 0; n < CNPB; ++n)
    q_lds[n][t] = q[(size_t)(node0 + n) * CC + t];
  __syncthreads();

  float acc[CNPB];
  {
    const float bv = b1[t];
    #pragma unroll
    for (int n = 0; n < CNPB; ++n) acc[n] = bv;
  }
  for (int k = 0; k < CC; k += 4) {
    float w[4];
    #pragma unroll
    for (int r = 0; r < 4; ++r) w[r] = W1[(size_t)(k + r) * CC + t];
    #pragma unroll
    for (int n = 0; n < CNPB; ++n) {
      const float4 qv = *reinterpret_cast<const float4*>(&q_lds[n][k]);
      acc[n] = fmaf(qv.x, w[0], acc[n]);
      acc[n] = fmaf(qv.y, w[1], acc[n]);
      acc[n] = fmaf(qv.z, w[2], acc[n]);
      acc[n] = fmaf(qv.w, w[3], acc[n]);
    }
  }
  #pragma unroll
  for (int n = 0; n < CNPB; ++n) {
    const float v = acc[n];
    h_lds[n][t] = v / (1.0f + expf(-v));
  }
  __syncthreads();

  float y0[CNPB], y1[CNPB], y2[CNPB];
  {
    const float bb0 = b2[t], bb1 = b2[CC + t], bb2 = b2[2 * CC + t];
    #pragma unroll
    for (int n = 0; n < CNPB; ++n) { y0[n] = bb0; y1[n] = bb1; y2[n] = bb2; }
  }
  for (int k = 0; k < CC; k += 4) {
    float w0[4], w1[4], w2[4];
    #pragma unroll
    for (int r = 0; r < 4; ++r) {
      const size_t row = (size_t)(k + r) * TC;
      w0[r] = W2[row + t];
      w1[r] = W2[row + CC + t];
      w2[r] = W2[row + 2 * CC + t];
    }
    #pragma unroll
    for (int n = 0; n < CNPB; ++n) {
      const float4 hv = *reinterpret_cast<const float4*>(&h_lds[n][k]);
      y0[n] = fmaf(hv.x, w0[0], y0[n]); y0[n] = fmaf(hv.y, w0[1], y0[n]);
      y0[n] = fmaf(hv.z, w0[2], y0[n]); y0[n] = fmaf(hv.w, w0[3], y0[n]);
      y1[n] = fmaf(hv.x, w1[0], y1[n]); y1[n] = fmaf(hv.y, w1[1], y1[n]);
      y1[n] = fmaf(hv.z, w1[2], y1[n]); y1[n] = fmaf(hv.w, w1[3], y1[n]);
      y2[n] = fmaf(hv.x, w2[0], y2[n]); y2[n] = fmaf(hv.y, w2[1], y2[n]);
      y2[n] = fmaf(hv.z, w2[2], y2[n]); y2[n] = fmaf(hv.w, w2[3], y2[n]);
    }
  }
  #pragma unroll
  for (int n = 0; n < CNPB; ++n) {
    const size_t base = (size_t)(node0 + n) * TC;
    x[base + t]          = y0[n];
    x[base + CC + t]     = y1[n];
    x[base + 2 * CC + t] = y2[n];
  }
}

// ---------------------------------------------------------------------------
// Gather (packed path): one block of 384 threads per node; thread c owns
// filter column c (weights in 20 regs). Hot loop reads SEQUENTIAL packed
// rows (no indirection, no cos); only x[j]/mu[j] are gathered.
// ---------------------------------------------------------------------------
#define GTH 384
__global__ __launch_bounds__(GTH) void gather_packed_kernel(
    const float* __restrict__ packed,
    const float* __restrict__ Wf, const float* __restrict__ bf,
    const float* __restrict__ x, const float* __restrict__ mu_in,
    const float* __restrict__ q_in, const int* __restrict__ offsets,
    float* __restrict__ qout, float* __restrict__ muout) {
  __shared__ float red[3][CC];
  const int c = threadIdx.x;
  const int i = blockIdx.x;
  const int grp = c >> 7;          // wave-uniform
  const int ch = c & 127;

  float wreg[BB];
  #pragma unroll
  for (int b = 0; b < BB; ++b) wreg[b] = Wf[b * TC + c];
  const float bfc = bf[c];

  const int start = offsets[i];
  const int end = offsets[i + 1];
  float a0 = 0.f, a1 = 0.f, a2 = 0.f;

  for (int k = start; k < end; ++k) {
    const float4* p4 = reinterpret_cast<const float4*>(packed) + (size_t)k * (PKF / 4);
    const float4 h0 = p4[0];           // {j, fc, v0, v1}
    const int j = __float_as_int(h0.x);
    const float4 h1 = p4[1];           // {v2, fa0, fa1, fa2}
    const float4 h2 = p4[2];           // fa3..fa6
    const float4 h3 = p4[3];           // fa7..fa10
    const float4 h4 = p4[4];           // fa11..fa14
    const float4 h5 = p4[5];           // fa15..fa18
    const float4 h6 = p4[6];           // {fa19, pad, pad, pad}

    const float xr = x[(size_t)j * TC + c];   // coalesced row read

    float ws = h0.y * bfc;                    // fc * bf[c]
    ws = fmaf(h1.y, wreg[0], ws);  ws = fmaf(h1.z, wreg[1], ws);
    ws = fmaf(h1.w, wreg[2], ws);  ws = fmaf(h2.x, wreg[3], ws);
    ws = fmaf(h2.y, wreg[4], ws);  ws = fmaf(h2.z, wreg[5], ws);
    ws = fmaf(h2.w, wreg[6], ws);  ws = fmaf(h3.x, wreg[7], ws);
    ws = fmaf(h3.y, wreg[8], ws);  ws = fmaf(h3.z, wreg[9], ws);
    ws = fmaf(h3.w, wreg[10], ws); ws = fmaf(h4.x, wreg[11], ws);
    ws = fmaf(h4.y, wreg[12], ws); ws = fmaf(h4.z, wreg[13], ws);
    ws = fmaf(h4.w, wreg[14], ws); ws = fmaf(h5.x, wreg[15], ws);
    ws = fmaf(h5.y, wreg[16], ws); ws = fmaf(h5.z, wreg[17], ws);
    ws = fmaf(h5.w, wreg[18], ws); ws = fmaf(h6.x, wreg[19], ws);

    const float xv = xr * ws;
    if (grp == 0) {
      a0 += xv;                                       // dq
    } else if (grp == 1) {
      a0 = fmaf(xv, h0.z, a0);                        // dmuR * versor
      a1 = fmaf(xv, h0.w, a1);
      a2 = fmaf(xv, h1.x, a2);
    } else {
      const float* muj = mu_in + (size_t)j * TC + ch;
      a0 = fmaf(xv, muj[0], a0);                      // dmumu * mu[j]
      a1 = fmaf(xv, muj[CC], a1);
      a2 = fmaf(xv, muj[2 * CC], a2);
    }
  }

  if (grp == 1) { red[0][ch] = a0; red[1][ch] = a1; red[2][ch] = a2; }
  __syncthreads();

  if (grp == 0) {
    qout[(size_t)i * CC + ch] = q_in[(size_t)i * CC + ch] + a0;
  } else if (grp == 2) {
    const size_t mb = (size_t)i * TC;
    muout[mb + ch]          = mu_in[mb + ch]          + red[0][ch] + a0;
    muout[mb + CC + ch]     = mu_in[mb + CC + ch]     + red[1][ch] + a1;
    muout[mb + 2 * CC + ch] = mu_in[mb + 2 * CC + ch] + red[2][ch] + a2;
  }
}

// fallback gather (round-3 style, edge_list indirection) for small ws
__global__ __launch_bounds__(GTH) void gather_list_kernel(
    const int* __restrict__ eidx, const float* __restrict__ ew,
    const float* __restrict__ evers, const float* __restrict__ eattr,
    const float* __restrict__ Wf, const float* __restrict__ bf,
    const float* __restrict__ x, const float* __restrict__ mu_in,
    const float* __restrict__ q_in,
    const int* __restrict__ offsets, const int* __restrict__ edge_list,
    float* __restrict__ qout, float* __restrict__ muout) {
  __shared__ float red[3][CC];
  const int c = threadIdx.x;
  const int i = blockIdx.x;
  const int grp = c >> 7;
  const int ch = c & 127;
  float wreg[BB];
  #pragma unroll
  for (int b = 0; b < BB; ++b) wreg[b] = Wf[b * TC + c];
  const float bfc = bf[c];
  const int start = offsets[i];
  const int end = offsets[i + 1];
  float a0 = 0.f, a1 = 0.f, a2 = 0.f;
  for (int k = start; k < end; ++k) {
    const int e = edge_list[k];
    const int j = eidx[NEDGES + e];
    const float w = ew[e];
    const float fc = (w < RCUT_F)
        ? 0.5f * (cosf(PI_F * (1.0f / RCUT_F) * w) + 1.0f) : 0.0f;
    const float2* ae2 = reinterpret_cast<const float2*>(eattr + (size_t)e * BB);
    float wsum = bfc;
    #pragma unroll
    for (int b = 0; b < BB / 2; ++b) {
      const float2 a = ae2[b];
      wsum = fmaf(a.x, wreg[2 * b], wsum);
      wsum = fmaf(a.y, wreg[2 * b + 1], wsum);
    }
    wsum *= fc;
    const float xv = x[(size_t)j * TC + c] * wsum;
    if (grp == 0) {
      a0 += xv;
    } else if (grp == 1) {
      const float v0 = evers[(size_t)e * 3];
      const float v1 = evers[(size_t)e * 3 + 1];
      const float v2 = evers[(size_t)e * 3 + 2];
      a0 = fmaf(xv, v0, a0); a1 = fmaf(xv, v1, a1); a2 = fmaf(xv, v2, a2);
    } else {
      const float* muj = mu_in + (size_t)j * TC + ch;
      a0 = fmaf(xv, muj[0], a0);
      a1 = fmaf(xv, muj[CC], a1);
      a2 = fmaf(xv, muj[2 * CC], a2);
    }
  }
  if (grp == 1) { red[0][ch] = a0; red[1][ch] = a1; red[2][ch] = a2; }
  __syncthreads();
  if (grp == 0) {
    qout[(size_t)i * CC + ch] = q_in[(size_t)i * CC + ch] + a0;
  } else if (grp == 2) {
    const size_t mb = (size_t)i * TC;
    muout[mb + ch]          = mu_in[mb + ch]          + red[0][ch] + a0;
    muout[mb + CC + ch]     = mu_in[mb + CC + ch]     + red[1][ch] + a1;
    muout[mb + 2 * CC + ch] = mu_in[mb + 2 * CC + ch] + red[2][ch] + a2;
  }
}

// ---------------------------------------------------------------------------
// Mixing kernel: 16 nodes per block, 128 threads. mu_V registers are
// released after norm+dot to keep VGPR pressure in range.
// ---------------------------------------------------------------------------
#define MNPB 16
__global__ __launch_bounds__(128) void mix_kernel(
    const float* __restrict__ Wmix, const float* __restrict__ Wm1,
    const float* __restrict__ bm1, const float* __restrict__ Wm2,
    const float* __restrict__ bm2, float* __restrict__ qout,
    float* __restrict__ muout) {
  __shared__ __align__(16) float mu_lds[MNPB][3][CC];   // 24 KB
  __shared__ __align__(16) float ctx_lds[MNPB][2 * CC]; // 16 KB
  __shared__ __align__(16) float h2_lds[MNPB][CC];      // 8 KB

  const int t = threadIdx.x;
  const int node0 = blockIdx.x * MNPB;

  #pragma unroll
  for (int n = 0; n < MNPB; ++n) {
    const size_t mb = (size_t)(node0 + n) * TC;
    mu_lds[n][0][t] = muout[mb + t];
    mu_lds[n][1][t] = muout[mb + CC + t];
    mu_lds[n][2][t] = muout[mb + 2 * CC + t];
    ctx_lds[n][t] = qout[(size_t)(node0 + n) * CC + t];
  }
  __syncthreads();

  float mW[MNPB][3], sdot[MNPB];
  {
    float mV[MNPB][3];
    #pragma unroll
    for (int n = 0; n < MNPB; ++n)
      #pragma unroll
      for (int v = 0; v < 3; ++v) { mV[n][v] = 0.0f; mW[n][v] = 0.0f; }

    for (int c = 0; c < CC; c += 4) {
      float wv[4], ww[4];
      #pragma unroll
      for (int r = 0; r < 4; ++r) {
        const size_t row = (size_t)(c + r) * (2 * CC);
        wv[r] = Wmix[row + t];
        ww[r] = Wmix[row + CC + t];
      }
      #pragma unroll
      for (int n = 0; n < MNPB; ++n) {
        #pragma unroll
        for (int v = 0; v < 3; ++v) {
          const float4 m = *reinterpret_cast<const float4*>(&mu_lds[n][v][c]);
          float a = mV[n][v], b = mW[n][v];
          a = fmaf(m.x, wv[0], a); a = fmaf(m.y, wv[1], a);
          a = fmaf(m.z, wv[2], a); a = fmaf(m.w, wv[3], a);
          b = fmaf(m.x, ww[0], b); b = fmaf(m.y, ww[1], b);
          b = fmaf(m.z, ww[2], b); b = fmaf(m.w, ww[3], b);
          mV[n][v] = a; mW[n][v] = b;
        }
      }
    }
    #pragma unroll
    for (int n = 0; n < MNPB; ++n) {
      const float ss = mV[n][0] * mV[n][0] + mV[n][1] * mV[n][1] + mV[n][2] * mV[n][2];
      ctx_lds[n][CC + t] = sqrtf(ss + 1e-8f);
      sdot[n] = mV[n][0] * mW[n][0] + mV[n][1] * mW[n][1] + mV[n][2] * mW[n][2];
    }
  } // mV dies here
  __syncthreads();

  float acc[MNPB];
  {
    const float bv = bm1[t];
    #pragma unroll
    for (int n = 0; n < MNPB; ++n) acc[n] = bv;
  }
  for (int k = 0; k < 2 * CC; k += 4) {
    float w[4];
    #pragma unroll
    for (int r = 0; r < 4; ++r) w[r] = Wm1[(size_t)(k + r) * CC + t];
    #pragma unroll
    for (int n = 0; n < MNPB; ++n) {
      const float4 cx = *reinterpret_cast<const float4*>(&ctx_lds[n][k]);
      acc[n] = fmaf(cx.x, w[0], acc[n]); acc[n] = fmaf(cx.y, w[1], acc[n]);
      acc[n] = fmaf(cx.z, w[2], acc[n]); acc[n] = fmaf(cx.w, w[3], acc[n]);
    }
  }
  #pragma unroll
  for (int n = 0; n < MNPB; ++n) {
    const float v = acc[n];
    h2_lds[n][t] = v / (1.0f + expf(-v));
  }
  __syncthreads();

  float y0[MNPB], y1[MNPB], y2[MNPB];
  {
    const float bb0 = bm2[t], bb1 = bm2[CC + t], bb2 = bm2[2 * CC + t];
    #pragma unroll
    for (int n = 0; n < MNPB; ++n) { y0[n] = bb0; y1[n] = bb1; y2[n] = bb2; }
  }
  for (int k = 0; k < CC; k += 4) {
    float w0[4], w1[4], w2[4];
    #pragma unroll
    for (int r = 0; r < 4; ++r) {
      const size_t row = (size_t)(k + r) * TC;
      w0[r] = Wm2[row + t];
      w1[r] = Wm2[row + CC + t];
      w2[r] = Wm2[row + 2 * CC + t];
    }
    #pragma unroll
    for (int n = 0; n < MNPB; ++n) {
      const float4 h = *reinterpret_cast<const float4*>(&h2_lds[n][k]);
      y0[n] = fmaf(h.x, w0[0], y0[n]); y0[n] = fmaf(h.y, w0[1], y0[n]);
      y0[n] = fmaf(h.z, w0[2], y0[n]); y0[n] = fmaf(h.w, w0[3], y0[n]);
      y1[n] = fmaf(h.x, w1[0], y1[n]); y1[n] = fmaf(h.y, w1[1], y1[n]);
      y1[n] = fmaf(h.z, w1[2], y1[n]); y1[n] = fmaf(h.w, w1[3], y1[n]);
      y2[n] = fmaf(h.x, w2[0], y2[n]); y2[n] = fmaf(h.y, w2[1], y2[n]);
      y2[n] = fmaf(h.z, w2[2], y2[n]); y2[n] = fmaf(h.w, w2[3], y2[n]);
    }
  }

  #pragma unroll
  for (int n = 0; n < MNPB; ++n) {
    const float qnew = ctx_lds[n][t];
    qout[(size_t)(node0 + n) * CC + t] = qnew + y0[n] + y2[n] * sdot[n];
    const size_t mb = (size_t)(node0 + n) * TC;
    muout[mb + t]          = mu_lds[n][0][t] + y1[n] * mW[n][0];
    muout[mb + CC + t]     = mu_lds[n][1][t] + y1[n] * mW[n][1];
    muout[mb + 2 * CC + t] = mu_lds[n][2][t] + y1[n] * mW[n][2];
  }
}

// ---------------------------------------------------------------------------
extern "C" void kernel_launch(void* const* d_in, const int* in_sizes, int n_in,
                              void* d_out, int out_size, void* d_ws, size_t ws_size,
                              hipStream_t stream) {
  const float* q     = (const float*)d_in[0];
  const float* mu    = (const float*)d_in[1];
  const int*   eidx  = (const int*)d_in[2];
  const float* ew    = (const float*)d_in[3];
  const float* evers = (const float*)d_in[4];
  const float* eattr = (const float*)d_in[5];
  const float* Wf    = (const float*)d_in[6];
  const float* bf    = (const float*)d_in[7];
  const float* W1    = (const float*)d_in[8];
  const float* b1    = (const float*)d_in[9];
  const float* W2    = (const float*)d_in[10];
  const float* b2    = (const float*)d_in[11];
  const float* Wmix  = (const float*)d_in[12];
  const float* Wm1   = (const float*)d_in[13];
  const float* bm1   = (const float*)d_in[14];
  const float* Wm2   = (const float*)d_in[15];
  const float* bm2   = (const float*)d_in[16];

  float* out   = (float*)d_out;
  float* qout  = out;                                // [N, C]
  float* muout = out + (size_t)NNODES * CC;          // [N, 3, C]

  // workspace layout: packed | x | counts | offsets | (edge_list fallback)
  float* packed   = (float*)d_ws;                           // [E*28] floats
  float* x        = packed + (size_t)NEDGES * PKF;          // [N*3C]
  int*   counts   = (int*)(x + (size_t)NNODES * TC);        // [N]
  int*   offsets  = counts + NNODES;                        // [N+1]
  const size_t need_packed =
      ((size_t)NEDGES * PKF + (size_t)NNODES * TC) * 4 + (2 * NNODES + 2) * 4 + 256;
  const bool use_packed = ws_size >= need_packed;

  if (use_packed) {
    zero_counts_kernel<<<(NNODES + 255) / 256, 256, 0, stream>>>(counts);
    hist_kernel<<<(NEDGES + 255) / 256, 256, 0, stream>>>(eidx, counts);
    scan_kernel<<<1, 512, 0, stream>>>(counts, offsets);
    pack_scatter_kernel<<<(NEDGES + 255) / 256, 256, 0, stream>>>(
        eidx, ew, evers, eattr, offsets, counts, packed);
    ctx_net_kernel<<<NNODES / CNPB, 128, 0, stream>>>(q, W1, b1, W2, b2, x);
    gather_packed_kernel<<<NNODES, GTH, 0, stream>>>(
        packed, Wf, bf, x, mu, q, offsets, qout, muout);
  } else {
    // fallback: round-3 layout (x | counts | offsets | edge_list)
    float* xf        = (float*)d_ws;
    int*   countsf   = (int*)(xf + (size_t)NNODES * TC);
    int*   offsetsf  = countsf + NNODES;
    int*   edge_list = offsetsf + NNODES + 1;
    zero_counts_kernel<<<(NNODES + 255) / 256, 256, 0, stream>>>(countsf);
    hist_kernel<<<(NEDGES + 255) / 256, 256, 0, stream>>>(eidx, countsf);
    scan_kernel<<<1, 512, 0, stream>>>(countsf, offsetsf);
    scatter_kernel<<<(NEDGES + 255) / 256, 256, 0, stream>>>(eidx, offsetsf,
                                                             countsf, edge_list);
    ctx_net_kernel<<<NNODES / CNPB, 128, 0, stream>>>(q, W1, b1, W2, b2, xf);
    gather_list_kernel<<<NNODES, GTH, 0, stream>>>(eidx, ew, evers, eattr,
                                                   Wf, bf, xf, mu, q,
                                                   offsetsf, edge_list,
                                                   qout, muout);
  }
  mix_kernel<<<NNODES / MNPB, 128, 0, stream>>>(Wmix, Wm1, bm1, Wm2, bm2,
                                                qout, muout);
}

// Round 5
// 620.628 us; speedup vs baseline: 2.2231x; 1.2743x over previous
//
#include <hip/hip_runtime.h>
#include <math.h>

#define NNODES 20000
#define NEDGES 320000
#define CC 128          // channels
#define TC 384          // 3*C
#define BB 20           // basis dim
#define RCUT_F 5.0f
#define PI_F 3.14159265358979323846f
#define PKF 28          // packed floats per edge (112 B, float4-aligned)

// ---------------------------------------------------------------------------
// CSR build: zero -> histogram -> single-block scan -> pack+scatter
// ---------------------------------------------------------------------------
__global__ __launch_bounds__(256) void zero_counts_kernel(int* __restrict__ counts) {
  const int i = blockIdx.x * 256 + threadIdx.x;
  if (i < NNODES) counts[i] = 0;
}

__global__ __launch_bounds__(256) void hist_kernel(const int* __restrict__ eidx,
                                                   int* __restrict__ counts) {
  const int e = blockIdx.x * 256 + threadIdx.x;
  if (e < NEDGES) atomicAdd(&counts[eidx[e]], 1);
}

__global__ __launch_bounds__(512) void scan_kernel(int* __restrict__ counts,
                                                   int* __restrict__ offsets) {
  __shared__ int sums[512];
  const int t = threadIdx.x;
  const int chunk = 40;                       // ceil(20000/512)
  const int lo = t * chunk;
  const int hi = min(lo + chunk, NNODES);
  int s = 0;
  for (int i = lo; i < hi; ++i) s += counts[i];
  sums[t] = s;
  __syncthreads();
  for (int d = 1; d < 512; d <<= 1) {
    const int other = (t >= d) ? sums[t - d] : 0;
    __syncthreads();
    sums[t] += other;
    __syncthreads();
  }
  int run = sums[t] - s;                      // exclusive prefix
  for (int i = lo; i < hi; ++i) {
    offsets[i] = run;
    run += counts[i];
    counts[i] = 0;                            // re-zero: reused as scatter cursor
  }
  if (hi == NNODES) offsets[NNODES] = run;    // == NEDGES
}

// packed[pos] = { j(bits), fc, v0, v1, v2, fc*attrs[0..19], pad[3] }
__global__ __launch_bounds__(256) void pack_scatter_kernel(
    const int* __restrict__ eidx, const float* __restrict__ ew,
    const float* __restrict__ evers, const float* __restrict__ eattr,
    const int* __restrict__ offsets, int* __restrict__ counts,
    float* __restrict__ packed) {
  const int e = blockIdx.x * 256 + threadIdx.x;
  if (e >= NEDGES) return;
  const int i = eidx[e];
  const int j = eidx[NEDGES + e];
  const int pos = offsets[i] + atomicAdd(&counts[i], 1);
  const float w = ew[e];
  const float fc = (w < RCUT_F)
      ? 0.5f * (cosf(PI_F * (1.0f / RCUT_F) * w) + 1.0f) : 0.0f;
  float* p = packed + (size_t)pos * PKF;
  p[0] = __int_as_float(j);
  p[1] = fc;
  p[2] = evers[(size_t)e * 3];
  p[3] = evers[(size_t)e * 3 + 1];
  p[4] = evers[(size_t)e * 3 + 2];
  const float* ae = eattr + (size_t)e * BB;
  #pragma unroll
  for (int b = 0; b < BB; ++b) p[5 + b] = fc * ae[b];
}

// fallback (no packing) scatter for small ws
__global__ __launch_bounds__(256) void scatter_kernel(const int* __restrict__ eidx,
                                                      const int* __restrict__ offsets,
                                                      int* __restrict__ counts,
                                                      int* __restrict__ edge_list) {
  const int e = blockIdx.x * 256 + threadIdx.x;
  if (e < NEDGES) {
    const int i = eidx[e];
    const int pos = offsets[i] + atomicAdd(&counts[i], 1);
    edge_list[pos] = e;
  }
}

// ---------------------------------------------------------------------------
// Context net: x = silu(q@W1 + b1) @ W2 + b2      [N, 3C]
// 8 nodes per block, 128 threads, 8-row weight chunks (deep load pipeline).
// ---------------------------------------------------------------------------
#define CNPB 8
__global__ __launch_bounds__(128) void ctx_net_kernel(
    const float* __restrict__ q,
    const float* __restrict__ W1, const float* __restrict__ b1,
    const float* __restrict__ W2, const float* __restrict__ b2,
    float* __restrict__ x) {
  __shared__ __align__(16) float q_lds[CNPB][CC];
  __shared__ __align__(16) float h_lds[CNPB][CC];
  const int t = threadIdx.x;
  const int node0 = blockIdx.x * CNPB;

  #pragma unroll
  for (int n = 0; n < CNPB; ++n)
    q_lds[n][t] = q[(size_t)(node0 + n) * CC + t];
  __syncthreads();

  float acc[CNPB];
  {
    const float bv = b1[t];
    #pragma unroll
    for (int n = 0; n < CNPB; ++n) acc[n] = bv;
  }
  for (int k = 0; k < CC; k += 8) {
    float w[8];
    #pragma unroll
    for (int r = 0; r < 8; ++r) w[r] = W1[(size_t)(k + r) * CC + t];
    #pragma unroll
    for (int n = 0; n < CNPB; ++n) {
      const float4 q0 = *reinterpret_cast<const float4*>(&q_lds[n][k]);
      const float4 q1 = *reinterpret_cast<const float4*>(&q_lds[n][k + 4]);
      acc[n] = fmaf(q0.x, w[0], acc[n]); acc[n] = fmaf(q0.y, w[1], acc[n]);
      acc[n] = fmaf(q0.z, w[2], acc[n]); acc[n] = fmaf(q0.w, w[3], acc[n]);
      acc[n] = fmaf(q1.x, w[4], acc[n]); acc[n] = fmaf(q1.y, w[5], acc[n]);
      acc[n] = fmaf(q1.z, w[6], acc[n]); acc[n] = fmaf(q1.w, w[7], acc[n]);
    }
  }
  #pragma unroll
  for (int n = 0; n < CNPB; ++n) {
    const float v = acc[n];
    h_lds[n][t] = v / (1.0f + expf(-v));
  }
  __syncthreads();

  float y0[CNPB], y1[CNPB], y2[CNPB];
  {
    const float bb0 = b2[t], bb1 = b2[CC + t], bb2 = b2[2 * CC + t];
    #pragma unroll
    for (int n = 0; n < CNPB; ++n) { y0[n] = bb0; y1[n] = bb1; y2[n] = bb2; }
  }
  for (int k = 0; k < CC; k += 8) {
    float w0[8], w1[8], w2[8];
    #pragma unroll
    for (int r = 0; r < 8; ++r) {
      const size_t row = (size_t)(k + r) * TC;
      w0[r] = W2[row + t];
      w1[r] = W2[row + CC + t];
      w2[r] = W2[row + 2 * CC + t];
    }
    #pragma unroll
    for (int n = 0; n < CNPB; ++n) {
      const float4 h0 = *reinterpret_cast<const float4*>(&h_lds[n][k]);
      const float4 h1 = *reinterpret_cast<const float4*>(&h_lds[n][k + 4]);
      y0[n] = fmaf(h0.x, w0[0], y0[n]); y0[n] = fmaf(h0.y, w0[1], y0[n]);
      y0[n] = fmaf(h0.z, w0[2], y0[n]); y0[n] = fmaf(h0.w, w0[3], y0[n]);
      y0[n] = fmaf(h1.x, w0[4], y0[n]); y0[n] = fmaf(h1.y, w0[5], y0[n]);
      y0[n] = fmaf(h1.z, w0[6], y0[n]); y0[n] = fmaf(h1.w, w0[7], y0[n]);
      y1[n] = fmaf(h0.x, w1[0], y1[n]); y1[n] = fmaf(h0.y, w1[1], y1[n]);
      y1[n] = fmaf(h0.z, w1[2], y1[n]); y1[n] = fmaf(h0.w, w1[3], y1[n]);
      y1[n] = fmaf(h1.x, w1[4], y1[n]); y1[n] = fmaf(h1.y, w1[5], y1[n]);
      y1[n] = fmaf(h1.z, w1[6], y1[n]); y1[n] = fmaf(h1.w, w1[7], y1[n]);
      y2[n] = fmaf(h0.x, w2[0], y2[n]); y2[n] = fmaf(h0.y, w2[1], y2[n]);
      y2[n] = fmaf(h0.z, w2[2], y2[n]); y2[n] = fmaf(h0.w, w2[3], y2[n]);
      y2[n] = fmaf(h1.x, w2[4], y2[n]); y2[n] = fmaf(h1.y, w2[5], y2[n]);
      y2[n] = fmaf(h1.z, w2[6], y2[n]); y2[n] = fmaf(h1.w, w2[7], y2[n]);
    }
  }
  #pragma unroll
  for (int n = 0; n < CNPB; ++n) {
    const size_t base = (size_t)(node0 + n) * TC;
    x[base + t]          = y0[n];
    x[base + CC + t]     = y1[n];
    x[base + 2 * CC + t] = y2[n];
  }
}

// ---------------------------------------------------------------------------
// Gather (packed path): one block of 384 threads per node; thread c owns
// filter column c (weights in 20 regs). Unrolled x2: two independent edges
// per iteration so both packed rows + both x/mu gathers are in flight.
// ---------------------------------------------------------------------------
#define GTH 384

struct EdgeRegs { float4 h0, h1, h2, h3, h4, h5, h6; };

__device__ __forceinline__ EdgeRegs load_edge(const float4* __restrict__ p4,
                                              int k) {
  const float4* p = p4 + (size_t)k * (PKF / 4);
  EdgeRegs E;
  E.h0 = p[0]; E.h1 = p[1]; E.h2 = p[2]; E.h3 = p[3];
  E.h4 = p[4]; E.h5 = p[5]; E.h6 = p[6];
  return E;
}

__device__ __forceinline__ float filter_ws(const EdgeRegs& E,
                                           const float* wreg, float bfc) {
  float ws = E.h0.y * bfc;                    // fc * bf[c]
  ws = fmaf(E.h1.y, wreg[0], ws);  ws = fmaf(E.h1.z, wreg[1], ws);
  ws = fmaf(E.h1.w, wreg[2], ws);  ws = fmaf(E.h2.x, wreg[3], ws);
  ws = fmaf(E.h2.y, wreg[4], ws);  ws = fmaf(E.h2.z, wreg[5], ws);
  ws = fmaf(E.h2.w, wreg[6], ws);  ws = fmaf(E.h3.x, wreg[7], ws);
  ws = fmaf(E.h3.y, wreg[8], ws);  ws = fmaf(E.h3.z, wreg[9], ws);
  ws = fmaf(E.h3.w, wreg[10], ws); ws = fmaf(E.h4.x, wreg[11], ws);
  ws = fmaf(E.h4.y, wreg[12], ws); ws = fmaf(E.h4.z, wreg[13], ws);
  ws = fmaf(E.h4.w, wreg[14], ws); ws = fmaf(E.h5.x, wreg[15], ws);
  ws = fmaf(E.h5.y, wreg[16], ws); ws = fmaf(E.h5.z, wreg[17], ws);
  ws = fmaf(E.h5.w, wreg[18], ws); ws = fmaf(E.h6.x, wreg[19], ws);
  return ws;
}

__global__ __launch_bounds__(GTH) void gather_packed_kernel(
    const float* __restrict__ packed,
    const float* __restrict__ Wf, const float* __restrict__ bf,
    const float* __restrict__ x, const float* __restrict__ mu_in,
    const float* __restrict__ q_in, const int* __restrict__ offsets,
    float* __restrict__ qout, float* __restrict__ muout) {
  __shared__ float red[3][CC];
  const int c = threadIdx.x;
  const int i = blockIdx.x;
  const int grp = c >> 7;          // wave-uniform
  const int ch = c & 127;

  float wreg[BB];
  #pragma unroll
  for (int b = 0; b < BB; ++b) wreg[b] = Wf[b * TC + c];
  const float bfc = bf[c];

  const float4* p4 = reinterpret_cast<const float4*>(packed);
  const int start = offsets[i];
  const int end = offsets[i + 1];
  float a0 = 0.f, a1 = 0.f, a2 = 0.f;

  int k = start;
  for (; k + 1 < end; k += 2) {
    // issue both packed-row loads up front
    const EdgeRegs A = load_edge(p4, k);
    const EdgeRegs B = load_edge(p4, k + 1);
    const int jA = __float_as_int(A.h0.x);
    const int jB = __float_as_int(B.h0.x);
    // both gathers in flight
    const float xA = x[(size_t)jA * TC + c];
    const float xB = x[(size_t)jB * TC + c];
    float muA0, muA1, muA2, muB0, muB1, muB2;
    if (grp == 2) {
      const float* mA = mu_in + (size_t)jA * TC + ch;
      const float* mB = mu_in + (size_t)jB * TC + ch;
      muA0 = mA[0]; muA1 = mA[CC]; muA2 = mA[2 * CC];
      muB0 = mB[0]; muB1 = mB[CC]; muB2 = mB[2 * CC];
    }
    // filter math overlaps the gathers
    const float wsA = filter_ws(A, wreg, bfc);
    const float wsB = filter_ws(B, wreg, bfc);
    const float xvA = xA * wsA;
    const float xvB = xB * wsB;
    if (grp == 0) {
      a0 += xvA + xvB;
    } else if (grp == 1) {
      a0 = fmaf(xvA, A.h0.z, fmaf(xvB, B.h0.z, a0));
      a1 = fmaf(xvA, A.h0.w, fmaf(xvB, B.h0.w, a1));
      a2 = fmaf(xvA, A.h1.x, fmaf(xvB, B.h1.x, a2));
    } else {
      a0 = fmaf(xvA, muA0, fmaf(xvB, muB0, a0));
      a1 = fmaf(xvA, muA1, fmaf(xvB, muB1, a1));
      a2 = fmaf(xvA, muA2, fmaf(xvB, muB2, a2));
    }
  }
  if (k < end) {
    const EdgeRegs A = load_edge(p4, k);
    const int jA = __float_as_int(A.h0.x);
    const float xA = x[(size_t)jA * TC + c];
    const float wsA = filter_ws(A, wreg, bfc);
    const float xvA = xA * wsA;
    if (grp == 0) {
      a0 += xvA;
    } else if (grp == 1) {
      a0 = fmaf(xvA, A.h0.z, a0);
      a1 = fmaf(xvA, A.h0.w, a1);
      a2 = fmaf(xvA, A.h1.x, a2);
    } else {
      const float* mA = mu_in + (size_t)jA * TC + ch;
      a0 = fmaf(xvA, mA[0], a0);
      a1 = fmaf(xvA, mA[CC], a1);
      a2 = fmaf(xvA, mA[2 * CC], a2);
    }
  }

  if (grp == 1) { red[0][ch] = a0; red[1][ch] = a1; red[2][ch] = a2; }
  __syncthreads();

  if (grp == 0) {
    qout[(size_t)i * CC + ch] = q_in[(size_t)i * CC + ch] + a0;
  } else if (grp == 2) {
    const size_t mb = (size_t)i * TC;
    muout[mb + ch]          = mu_in[mb + ch]          + red[0][ch] + a0;
    muout[mb + CC + ch]     = mu_in[mb + CC + ch]     + red[1][ch] + a1;
    muout[mb + 2 * CC + ch] = mu_in[mb + 2 * CC + ch] + red[2][ch] + a2;
  }
}

// fallback gather (edge_list indirection) for small ws
__global__ __launch_bounds__(GTH) void gather_list_kernel(
    const int* __restrict__ eidx, const float* __restrict__ ew,
    const float* __restrict__ evers, const float* __restrict__ eattr,
    const float* __restrict__ Wf, const float* __restrict__ bf,
    const float* __restrict__ x, const float* __restrict__ mu_in,
    const float* __restrict__ q_in,
    const int* __restrict__ offsets, const int* __restrict__ edge_list,
    float* __restrict__ qout, float* __restrict__ muout) {
  __shared__ float red[3][CC];
  const int c = threadIdx.x;
  const int i = blockIdx.x;
  const int grp = c >> 7;
  const int ch = c & 127;
  float wreg[BB];
  #pragma unroll
  for (int b = 0; b < BB; ++b) wreg[b] = Wf[b * TC + c];
  const float bfc = bf[c];
  const int start = offsets[i];
  const int end = offsets[i + 1];
  float a0 = 0.f, a1 = 0.f, a2 = 0.f;
  for (int k = start; k < end; ++k) {
    const int e = edge_list[k];
    const int j = eidx[NEDGES + e];
    const float w = ew[e];
    const float fc = (w < RCUT_F)
        ? 0.5f * (cosf(PI_F * (1.0f / RCUT_F) * w) + 1.0f) : 0.0f;
    const float2* ae2 = reinterpret_cast<const float2*>(eattr + (size_t)e * BB);
    float wsum = bfc;
    #pragma unroll
    for (int b = 0; b < BB / 2; ++b) {
      const float2 a = ae2[b];
      wsum = fmaf(a.x, wreg[2 * b], wsum);
      wsum = fmaf(a.y, wreg[2 * b + 1], wsum);
    }
    wsum *= fc;
    const float xv = x[(size_t)j * TC + c] * wsum;
    if (grp == 0) {
      a0 += xv;
    } else if (grp == 1) {
      const float v0 = evers[(size_t)e * 3];
      const float v1 = evers[(size_t)e * 3 + 1];
      const float v2 = evers[(size_t)e * 3 + 2];
      a0 = fmaf(xv, v0, a0); a1 = fmaf(xv, v1, a1); a2 = fmaf(xv, v2, a2);
    } else {
      const float* muj = mu_in + (size_t)j * TC + ch;
      a0 = fmaf(xv, muj[0], a0);
      a1 = fmaf(xv, muj[CC], a1);
      a2 = fmaf(xv, muj[2 * CC], a2);
    }
  }
  if (grp == 1) { red[0][ch] = a0; red[1][ch] = a1; red[2][ch] = a2; }
  __syncthreads();
  if (grp == 0) {
    qout[(size_t)i * CC + ch] = q_in[(size_t)i * CC + ch] + a0;
  } else if (grp == 2) {
    const size_t mb = (size_t)i * TC;
    muout[mb + ch]          = mu_in[mb + ch]          + red[0][ch] + a0;
    muout[mb + CC + ch]     = mu_in[mb + CC + ch]     + red[1][ch] + a1;
    muout[mb + 2 * CC + ch] = mu_in[mb + 2 * CC + ch] + red[2][ch] + a2;
  }
}

// ---------------------------------------------------------------------------
// Mixing kernel: 8 nodes per block, 128 threads (24 KB LDS -> 6 blocks/CU),
// 8-row weight chunks for deep load pipelining. mu_V regs die after norm/dot.
// ---------------------------------------------------------------------------
#define MNPB 8
__global__ __launch_bounds__(128) void mix_kernel(
    const float* __restrict__ Wmix, const float* __restrict__ Wm1,
    const float* __restrict__ bm1, const float* __restrict__ Wm2,
    const float* __restrict__ bm2, float* __restrict__ qout,
    float* __restrict__ muout) {
  __shared__ __align__(16) float mu_lds[MNPB][3][CC];   // 12 KB
  __shared__ __align__(16) float ctx_lds[MNPB][2 * CC]; // 8 KB
  __shared__ __align__(16) float h2_lds[MNPB][CC];      // 4 KB

  const int t = threadIdx.x;
  const int node0 = blockIdx.x * MNPB;

  #pragma unroll
  for (int n = 0; n < MNPB; ++n) {
    const size_t mb = (size_t)(node0 + n) * TC;
    mu_lds[n][0][t] = muout[mb + t];
    mu_lds[n][1][t] = muout[mb + CC + t];
    mu_lds[n][2][t] = muout[mb + 2 * CC + t];
    ctx_lds[n][t] = qout[(size_t)(node0 + n) * CC + t];
  }
  __syncthreads();

  float mW[MNPB][3], sdot[MNPB];
  {
    float mV[MNPB][3];
    #pragma unroll
    for (int n = 0; n < MNPB; ++n)
      #pragma unroll
      for (int v = 0; v < 3; ++v) { mV[n][v] = 0.0f; mW[n][v] = 0.0f; }

    for (int c = 0; c < CC; c += 8) {
      float wv[8], ww[8];
      #pragma unroll
      for (int r = 0; r < 8; ++r) {
        const size_t row = (size_t)(c + r) * (2 * CC);
        wv[r] = Wmix[row + t];
        ww[r] = Wmix[row + CC + t];
      }
      #pragma unroll
      for (int n = 0; n < MNPB; ++n) {
        #pragma unroll
        for (int v = 0; v < 3; ++v) {
          const float4 m0 = *reinterpret_cast<const float4*>(&mu_lds[n][v][c]);
          const float4 m1 = *reinterpret_cast<const float4*>(&mu_lds[n][v][c + 4]);
          float a = mV[n][v], b = mW[n][v];
          a = fmaf(m0.x, wv[0], a); a = fmaf(m0.y, wv[1], a);
          a = fmaf(m0.z, wv[2], a); a = fmaf(m0.w, wv[3], a);
          a = fmaf(m1.x, wv[4], a); a = fmaf(m1.y, wv[5], a);
          a = fmaf(m1.z, wv[6], a); a = fmaf(m1.w, wv[7], a);
          b = fmaf(m0.x, ww[0], b); b = fmaf(m0.y, ww[1], b);
          b = fmaf(m0.z, ww[2], b); b = fmaf(m0.w, ww[3], b);
          b = fmaf(m1.x, ww[4], b); b = fmaf(m1.y, ww[5], b);
          b = fmaf(m1.z, ww[6], b); b = fmaf(m1.w, ww[7], b);
          mV[n][v] = a; mW[n][v] = b;
        }
      }
    }
    #pragma unroll
    for (int n = 0; n < MNPB; ++n) {
      const float ss = mV[n][0] * mV[n][0] + mV[n][1] * mV[n][1] + mV[n][2] * mV[n][2];
      ctx_lds[n][CC + t] = sqrtf(ss + 1e-8f);
      sdot[n] = mV[n][0] * mW[n][0] + mV[n][1] * mW[n][1] + mV[n][2] * mW[n][2];
    }
  } // mV dies here
  __syncthreads();

  float acc[MNPB];
  {
    const float bv = bm1[t];
    #pragma unroll
    for (int n = 0; n < MNPB; ++n) acc[n] = bv;
  }
  for (int k = 0; k < 2 * CC; k += 8) {
    float w[8];
    #pragma unroll
    for (int r = 0; r < 8; ++r) w[r] = Wm1[(size_t)(k + r) * CC + t];
    #pragma unroll
    for (int n = 0; n < MNPB; ++n) {
      const float4 c0 = *reinterpret_cast<const float4*>(&ctx_lds[n][k]);
      const float4 c1 = *reinterpret_cast<const float4*>(&ctx_lds[n][k + 4]);
      acc[n] = fmaf(c0.x, w[0], acc[n]); acc[n] = fmaf(c0.y, w[1], acc[n]);
      acc[n] = fmaf(c0.z, w[2], acc[n]); acc[n] = fmaf(c0.w, w[3], acc[n]);
      acc[n] = fmaf(c1.x, w[4], acc[n]); acc[n] = fmaf(c1.y, w[5], acc[n]);
      acc[n] = fmaf(c1.z, w[6], acc[n]); acc[n] = fmaf(c1.w, w[7], acc[n]);
    }
  }
  #pragma unroll
  for (int n = 0; n < MNPB; ++n) {
    const float v = acc[n];
    h2_lds[n][t] = v / (1.0f + expf(-v));
  }
  __syncthreads();

  float y0[MNPB], y1[MNPB], y2[MNPB];
  {
    const float bb0 = bm2[t], bb1 = bm2[CC + t], bb2 = bm2[2 * CC + t];
    #pragma unroll
    for (int n = 0; n < MNPB; ++n) { y0[n] = bb0; y1[n] = bb1; y2[n] = bb2; }
  }
  for (int k = 0; k < CC; k += 8) {
    float w0[8], w1[8], w2[8];
    #pragma unroll
    for (int r = 0; r < 8; ++r) {
      const size_t row = (size_t)(k + r) * TC;
      w0[r] = Wm2[row + t];
      w1[r] = Wm2[row + CC + t];
      w2[r] = Wm2[row + 2 * CC + t];
    }
    #pragma unroll
    for (int n = 0; n < MNPB; ++n) {
      const float4 h0 = *reinterpret_cast<const float4*>(&h2_lds[n][k]);
      const float4 h1 = *reinterpret_cast<const float4*>(&h2_lds[n][k + 4]);
      y0[n] = fmaf(h0.x, w0[0], y0[n]); y0[n] = fmaf(h0.y, w0[1], y0[n]);
      y0[n] = fmaf(h0.z, w0[2], y0[n]); y0[n] = fmaf(h0.w, w0[3], y0[n]);
      y0[n] = fmaf(h1.x, w0[4], y0[n]); y0[n] = fmaf(h1.y, w0[5], y0[n]);
      y0[n] = fmaf(h1.z, w0[6], y0[n]); y0[n] = fmaf(h1.w, w0[7], y0[n]);
      y1[n] = fmaf(h0.x, w1[0], y1[n]); y1[n] = fmaf(h0.y, w1[1], y1[n]);
      y1[n] = fmaf(h0.z, w1[2], y1[n]); y1[n] = fmaf(h0.w, w1[3], y1[n]);
      y1[n] = fmaf(h1.x, w1[4], y1[n]); y1[n] = fmaf(h1.y, w1[5], y1[n]);
      y1[n] = fmaf(h1.z, w1[6], y1[n]); y1[n] = fmaf(h1.w, w1[7], y1[n]);
      y2[n] = fmaf(h0.x, w2[0], y2[n]); y2[n] = fmaf(h0.y, w2[1], y2[n]);
      y2[n] = fmaf(h0.z, w2[2], y2[n]); y2[n] = fmaf(h0.w, w2[3], y2[n]);
      y2[n] = fmaf(h1.x, w2[4], y2[n]); y2[n] = fmaf(h1.y, w2[5], y2[n]);
      y2[n] = fmaf(h1.z, w2[6], y2[n]); y2[n] = fmaf(h1.w, w2[7], y2[n]);
    }
  }

  #pragma unroll
  for (int n = 0; n < MNPB; ++n) {
    const float qnew = ctx_lds[n][t];
    qout[(size_t)(node0 + n) * CC + t] = qnew + y0[n] + y2[n] * sdot[n];
    const size_t mb = (size_t)(node0 + n) * TC;
    muout[mb + t]          = mu_lds[n][0][t] + y1[n] * mW[n][0];
    muout[mb + CC + t]     = mu_lds[n][1][t] + y1[n] * mW[n][1];
    muout[mb + 2 * CC + t] = mu_lds[n][2][t] + y1[n] * mW[n][2];
  }
}

// ---------------------------------------------------------------------------
extern "C" void kernel_launch(void* const* d_in, const int* in_sizes, int n_in,
                              void* d_out, int out_size, void* d_ws, size_t ws_size,
                              hipStream_t stream) {
  const float* q     = (const float*)d_in[0];
  const float* mu    = (const float*)d_in[1];
  const int*   eidx  = (const int*)d_in[2];
  const float* ew    = (const float*)d_in[3];
  const float* evers = (const float*)d_in[4];
  const float* eattr = (const float*)d_in[5];
  const float* Wf    = (const float*)d_in[6];
  const float* bf    = (const float*)d_in[7];
  const float* W1    = (const float*)d_in[8];
  const float* b1    = (const float*)d_in[9];
  const float* W2    = (const float*)d_in[10];
  const float* b2    = (const float*)d_in[11];
  const float* Wmix  = (const float*)d_in[12];
  const float* Wm1   = (const float*)d_in[13];
  const float* bm1   = (const float*)d_in[14];
  const float* Wm2   = (const float*)d_in[15];
  const float* bm2   = (const float*)d_in[16];

  float* out   = (float*)d_out;
  float* qout  = out;                                // [N, C]
  float* muout = out + (size_t)NNODES * CC;          // [N, 3, C]

  // workspace layout: packed | x | counts | offsets
  float* packed   = (float*)d_ws;                           // [E*28] floats
  float* x        = packed + (size_t)NEDGES * PKF;          // [N*3C]
  int*   counts   = (int*)(x + (size_t)NNODES * TC);        // [N]
  int*   offsets  = counts + NNODES;                        // [N+1]
  const size_t need_packed =
      ((size_t)NEDGES * PKF + (size_t)NNODES * TC) * 4 + (2 * NNODES + 2) * 4 + 256;
  const bool use_packed = ws_size >= need_packed;

  if (use_packed) {
    zero_counts_kernel<<<(NNODES + 255) / 256, 256, 0, stream>>>(counts);
    hist_kernel<<<(NEDGES + 255) / 256, 256, 0, stream>>>(eidx, counts);
    scan_kernel<<<1, 512, 0, stream>>>(counts, offsets);
    pack_scatter_kernel<<<(NEDGES + 255) / 256, 256, 0, stream>>>(
        eidx, ew, evers, eattr, offsets, counts, packed);
    ctx_net_kernel<<<NNODES / CNPB, 128, 0, stream>>>(q, W1, b1, W2, b2, x);
    gather_packed_kernel<<<NNODES, GTH, 0, stream>>>(
        packed, Wf, bf, x, mu, q, offsets, qout, muout);
  } else {
    // fallback layout (x | counts | offsets | edge_list)
    float* xf        = (float*)d_ws;
    int*   countsf   = (int*)(xf + (size_t)NNODES * TC);
    int*   offsetsf  = countsf + NNODES;
    int*   edge_list = offsetsf + NNODES + 1;
    zero_counts_kernel<<<(NNODES + 255) / 256, 256, 0, stream>>>(countsf);
    hist_kernel<<<(NEDGES + 255) / 256, 256, 0, stream>>>(eidx, countsf);
    scan_kernel<<<1, 512, 0, stream>>>(countsf, offsetsf);
    scatter_kernel<<<(NEDGES + 255) / 256, 256, 0, stream>>>(eidx, offsetsf,
                                                             countsf, edge_list);
    ctx_net_kernel<<<NNODES / CNPB, 128, 0, stream>>>(q, W1, b1, W2, b2, xf);
    gather_list_kernel<<<NNODES, GTH, 0, stream>>>(eidx, ew, evers, eattr,
                                                   Wf, bf, xf, mu, q,
                                                   offsetsf, edge_list,
                                                   qout, muout);
  }
  mix_kernel<<<NNODES / MNPB, 128, 0, stream>>>(Wmix, Wm1, bm1, Wm2, bm2,
                                                qout, muout);
}